// Round 3
// baseline (643.111 us; speedup 1.0000x reference)
//
#include <hip/hip_runtime.h>
#include <stdint.h>

// Problem constants (match reference)
#define SLAB 8192    // SL
#define SUNL 16384   // SU
#define DIMX 1024
#define HID1 2048
#define HID2 512
#define KTRIES 8
#define MTOT (SLAB + SUNL)   // 24576

typedef __attribute__((ext_vector_type(8))) short bf16x8;    // 8 bf16 = 4 VGPRs
typedef __attribute__((ext_vector_type(4))) float f32x4;

// fp32 -> bf16 round-to-nearest-even
__device__ __forceinline__ unsigned short f2bf(float f) {
  union { float f; uint32_t u; } c; c.f = f;
  return (unsigned short)((c.u + 0x7fffu + ((c.u >> 16) & 1u)) >> 16);
}

// async global->LDS, 16B per lane; lds dest = wave-uniform base + lane*16
__device__ __forceinline__ void async16(const void* g, void* l) {
  __builtin_amdgcn_global_load_lds(
      (const __attribute__((address_space(1))) unsigned int*)g,
      (__attribute__((address_space(3))) unsigned int*)l,
      16, 0, 0);
}

// ---------------------------------------------------------------------------
// Threefry2x32 (JAX-compatible, 20 rounds)
// ---------------------------------------------------------------------------
struct U2 { uint32_t x, y; };

__device__ __forceinline__ U2 threefry(uint32_t k0, uint32_t k1, uint32_t x0, uint32_t x1) {
  uint32_t ks2 = k0 ^ k1 ^ 0x1BD11BDAu;
  x0 += k0; x1 += k1;
#define TF_R(r) { x0 += x1; x1 = (x1 << (r)) | (x1 >> (32 - (r))); x1 ^= x0; }
  TF_R(13) TF_R(15) TF_R(26) TF_R(6)
  x0 += k1; x1 += ks2 + 1u;
  TF_R(17) TF_R(29) TF_R(16) TF_R(24)
  x0 += ks2; x1 += k0 + 2u;
  TF_R(13) TF_R(15) TF_R(26) TF_R(6)
  x0 += k0; x1 += k1 + 3u;
  TF_R(17) TF_R(29) TF_R(16) TF_R(24)
  x0 += k1; x1 += ks2 + 4u;
  TF_R(13) TF_R(15) TF_R(26) TF_R(6)
  x0 += ks2; x1 += k0 + 5u;
#undef TF_R
  return {x0, x1};
}

// ---------------------------------------------------------------------------
// prep_kernel: one launch for cast(X_l|X_u), transpose-cast W1, W2, and pairs.
// ---------------------------------------------------------------------------
#define XL_BLOCKS (SLAB * DIMX / 4 / 256)           // 8192
#define CAST_BLOCKS (MTOT * DIMX / 4 / 256)         // 24576
#define T1_NBX (HID1 / 32)                          // 64
#define T1_BLOCKS ((HID1 / 32) * (DIMX / 32))       // 2048
#define T2_NBX (HID2 / 32)                          // 16
#define T2_BLOCKS ((HID2 / 32) * (HID1 / 32))       // 1024
#define PAIR_BLOCKS (SUNL / 256)                    // 64
#define PREP_BLOCKS (CAST_BLOCKS + T1_BLOCKS + T2_BLOCKS + PAIR_BLOCKS)

__global__ __launch_bounds__(256) void prep_kernel(
    const float* __restrict__ Xl, const float* __restrict__ Xu,
    const float* __restrict__ W1, const float* __restrict__ W2,
    const float* __restrict__ y_l, const float* __restrict__ y_u,
    unsigned short* __restrict__ X_bf, unsigned short* __restrict__ W1T,
    unsigned short* __restrict__ W2T,
    int* __restrict__ ia, int* __restrict__ ib, float* __restrict__ kv)
{
  __shared__ float t[32][33];
  int b = blockIdx.x;
  int tid = threadIdx.x;

  if (b < CAST_BLOCKS) {
    const float* src; size_t i, doff;
    if (b < XL_BLOCKS) { src = Xl; i = (size_t)b * 256 + tid; doff = 0; }
    else { src = Xu; i = (size_t)(b - XL_BLOCKS) * 256 + tid; doff = (size_t)SLAB * DIMX / 4; }
    float4 v = ((const float4*)src)[i];
    ushort4 o;
    o.x = f2bf(v.x); o.y = f2bf(v.y); o.z = f2bf(v.z); o.w = f2bf(v.w);
    ((ushort4*)X_bf)[doff + i] = o;
  } else if (b < CAST_BLOCKS + T1_BLOCKS + T2_BLOCKS) {
    const float* W; unsigned short* WT; int K, N, bx, by;
    if (b < CAST_BLOCKS + T1_BLOCKS) {
      int tb = b - CAST_BLOCKS;
      W = W1; WT = W1T; K = DIMX; N = HID1; bx = tb % T1_NBX; by = tb / T1_NBX;
    } else {
      int tb = b - CAST_BLOCKS - T1_BLOCKS;
      W = W2; WT = W2T; K = HID1; N = HID2; bx = tb % T2_NBX; by = tb / T2_NBX;
    }
    int k0 = by * 32, n0 = bx * 32;
    int tx = tid & 31, ty = tid >> 5;
#pragma unroll
    for (int i = 0; i < 32; i += 8)
      t[ty + i][tx] = W[(size_t)(k0 + ty + i) * N + n0 + tx];
    __syncthreads();
#pragma unroll
    for (int i = 0; i < 32; i += 8)
      WT[(size_t)(n0 + ty + i) * K + k0 + tx] = f2bf(t[tx][ty + i]);
  } else {
    // pair sampling (verified R1: partitionable threefry, bits1^bits2, &8191)
    int r = (b - CAST_BLOCKS - T1_BLOCKS - T2_BLOCKS) * 256 + tid;
    U2 ka  = threefry(0u, 42u, 0u, 0u);
    U2 kb  = threefry(0u, 42u, 0u, 1u);
    U2 k2a = threefry(ka.x, ka.y, 0u, 1u);
    U2 k2b = threefry(kb.x, kb.y, 0u, 1u);
    int iav[KTRIES], ibv[KTRIES];
#pragma unroll
    for (int c = 0; c < KTRIES; ++c) {
      uint32_t tt = (uint32_t)(r * KTRIES + c);
      U2 oa = threefry(k2a.x, k2a.y, 0u, tt);
      U2 ob = threefry(k2b.x, k2b.y, 0u, tt);
      iav[c] = (int)((oa.x ^ oa.y) & (SLAB - 1));
      ibv[c] = (int)((ob.x ^ ob.y) & (SLAB - 1));
    }
    int a = iav[0], bb2 = ibv[0];
#pragma unroll
    for (int c = 0; c < KTRIES; ++c) {
      if (iav[c] != ibv[c] && y_l[iav[c]] != y_l[ibv[c]]) { a = iav[c]; bb2 = ibv[c]; break; }
    }
    float ya = y_l[a], yb = y_l[bb2];
    ia[r] = a; ib[r] = bb2; kv[r] = (y_u[r] - yb) / (ya - yb);
  }
}

// ---------------------------------------------------------------------------
// bf16 MFMA GEMM, 256x256 tile, BK=64, CROSS-TILE SOFTWARE PIPELINE (R3):
//   - 512 threads = 8 waves (2M x 4N); wave tile 128x64 = 8x4 of 16x16x32.
//     LDS 128 KB double-buffer -> 1 block/CU (2 waves/SIMD): no cross-block
//     fill, so in-wave overlap is mandatory.
//   - R2 failure mode: tile-start burst (192 b128/CU ~ 2300cyc at 85 B/cyc)
//     serialized against MFMA (~2070cyc) -> MfmaUtil 36%. Fix: rotate q3/q4
//     of tile t-1 (32 pure-register MFMA, ~1240cyc/CU) INTO tile t's read
//     burst. Per-iteration order:
//       a0-reads(t) | S1 | q3(t-1) | b0-reads(t) | q4(t-1) | b1/a1-reads(t)
//       | lgkm(12) q1(t) | lgkm(8) q2(t) | lgkm(0) BAR1 | S2(t+2)
//       | vmcnt(6) BAR2
//     (read order a0:8,b0:4,b1:4,a1:8; DS completes in order -> counted
//      lgkm gates exact; sched_barrier(0) pins group order, rule #18.)
//   - 2 barriers/tile. BAR1 = all waves drained reads of cur -> S2 into cur
//     safe. BAR2 after vmcnt -> tile t+1 resident (needs S2@t-1 + S1@t:
//     outstanding 14 -> vmcnt(6) drains the 8 oldest; 6 left = S2@t = t+2
//     partial). S1@t -> other buf safe: reads of t-1 drained at BAR1@t-1.
//   - Per-acc-element K accumulation order unchanged vs R0/R1/R2
//     (q1/q2 at iter t, q3/q4 at iter t+1, still monotone in t)
//     -> bit-identical output.
//   - XOR swizzle (T2) unchanged: 0 bank conflicts measured.
//   - Epilogue j-innermost (R2-verified: WRITE_SIZE == output size).
//   - VGPR: peak liveness ~ acc(128) + old{a1,b1} + new{a0,b0} = 224 + addr.
//     Under the 256 cap of __launch_bounds__(512,2); watch for spill.
// ---------------------------------------------------------------------------
#define GROUP_M 8
#define MFMA_B16(a, b, c) __builtin_amdgcn_mfma_f32_16x16x32_bf16(a, b, c, 0, 0, 0)
#define SBAR __builtin_amdgcn_sched_barrier(0)

struct FragSet { bf16x8 a0[4][2], a1[4][2], b0[2][2], b1[2][2]; };

template<bool M2P, bool M1, bool S1F, bool S2F, int VMC, bool BARS>
__device__ __forceinline__ void ktile(
    FragSet& nf, FragSet& of,
    unsigned short* Ac, unsigned short* Bc, unsigned short* Ao,
    const unsigned short* gA, const unsigned short* gB,
    int K, int k1, int k2, int ldst,
    int abase, int bbase, int sw0, int sw1,
    f32x4 (&acc)[8][4])
{
  if (M1) {  // R-a0: 8 reads
#pragma unroll
    for (int i = 0; i < 4; ++i) {
      nf.a0[i][0] = *(const bf16x8*)(Ac + abase + i * 1024 + sw0);
      nf.a0[i][1] = *(const bf16x8*)(Ac + abase + i * 1024 + sw1);
    }
    SBAR;
  }
  if (S1F) {  // stage A c1,c3 of t+1 -> other buf (reads of t-1 drained @BAR1(t-1))
    async16(gA + (size_t)64 * K + k1,  Ao + 4096 + ldst);
    async16(gA + (size_t)192 * K + k1, Ao + 12288 + ldst);
    SBAR;
  }
  if (M2P) {  // q3(t-1): old a1 x old b0 (pure register) -- overlaps read drain
    __builtin_amdgcn_s_setprio(1);
#pragma unroll
    for (int i = 0; i < 4; ++i)
#pragma unroll
      for (int j = 0; j < 2; ++j) {
        acc[i + 4][j] = MFMA_B16(of.a1[i][0], of.b0[j][0], acc[i + 4][j]);
        acc[i + 4][j] = MFMA_B16(of.a1[i][1], of.b0[j][1], acc[i + 4][j]);
      }
    __builtin_amdgcn_s_setprio(0);
    SBAR;
  }
  if (M1) {  // R-b0: 4 reads
#pragma unroll
    for (int j = 0; j < 2; ++j) {
      nf.b0[j][0] = *(const bf16x8*)(Bc + bbase + j * 1024 + sw0);
      nf.b0[j][1] = *(const bf16x8*)(Bc + bbase + j * 1024 + sw1);
    }
    SBAR;
  }
  if (M2P) {  // q4(t-1): old a1 x old b1
    __builtin_amdgcn_s_setprio(1);
#pragma unroll
    for (int i = 0; i < 4; ++i)
#pragma unroll
      for (int j = 0; j < 2; ++j) {
        acc[i + 4][j + 2] = MFMA_B16(of.a1[i][0], of.b1[j][0], acc[i + 4][j + 2]);
        acc[i + 4][j + 2] = MFMA_B16(of.a1[i][1], of.b1[j][1], acc[i + 4][j + 2]);
      }
    __builtin_amdgcn_s_setprio(0);
    SBAR;
  }
  if (M1) {
    // R-b1: 4 reads, R-a1: 8 reads
#pragma unroll
    for (int j = 0; j < 2; ++j) {
      nf.b1[j][0] = *(const bf16x8*)(Bc + bbase + (j + 2) * 1024 + sw0);
      nf.b1[j][1] = *(const bf16x8*)(Bc + bbase + (j + 2) * 1024 + sw1);
    }
#pragma unroll
    for (int i = 0; i < 4; ++i) {
      nf.a1[i][0] = *(const bf16x8*)(Ac + abase + (i + 4) * 1024 + sw0);
      nf.a1[i][1] = *(const bf16x8*)(Ac + abase + (i + 4) * 1024 + sw1);
    }
    SBAR;
    // q1: a0 x b0  (first 12 reads; 24 issued -> wait to <=12)
    asm volatile("s_waitcnt lgkmcnt(12)" ::: "memory");
    SBAR;
    __builtin_amdgcn_s_setprio(1);
#pragma unroll
    for (int i = 0; i < 4; ++i)
#pragma unroll
      for (int j = 0; j < 2; ++j) {
        acc[i][j] = MFMA_B16(nf.a0[i][0], nf.b0[j][0], acc[i][j]);
        acc[i][j] = MFMA_B16(nf.a0[i][1], nf.b0[j][1], acc[i][j]);
      }
    __builtin_amdgcn_s_setprio(0);
    // q2: a0 x b1  (first 16 reads)
    asm volatile("s_waitcnt lgkmcnt(8)" ::: "memory");
    SBAR;
    __builtin_amdgcn_s_setprio(1);
#pragma unroll
    for (int i = 0; i < 4; ++i)
#pragma unroll
      for (int j = 0; j < 2; ++j) {
        acc[i][j + 2] = MFMA_B16(nf.a0[i][0], nf.b1[j][0], acc[i][j + 2]);
        acc[i][j + 2] = MFMA_B16(nf.a0[i][1], nf.b1[j][1], acc[i][j + 2]);
      }
    __builtin_amdgcn_s_setprio(0);
    asm volatile("s_waitcnt lgkmcnt(0)" ::: "memory");
    SBAR;
  }
  if (BARS) __builtin_amdgcn_s_barrier();   // BAR1
  if (S2F) {  // stage A c0,c2 + B c0..c3 of t+2 -> cur buf (safe by BAR1)
    async16(gA + k2,                   Ac + ldst);
    async16(gA + (size_t)128 * K + k2, Ac + 8192 + ldst);
    async16(gB + k2,                   Bc + ldst);
    async16(gB + (size_t)64 * K + k2,  Bc + 4096 + ldst);
    async16(gB + (size_t)128 * K + k2, Bc + 8192 + ldst);
    async16(gB + (size_t)192 * K + k2, Bc + 12288 + ldst);
    SBAR;
  }
  if (VMC == 6)      asm volatile("s_waitcnt vmcnt(6)" ::: "memory");
  else if (VMC == 0) asm volatile("s_waitcnt vmcnt(0)" ::: "memory");
  if (BARS) __builtin_amdgcn_s_barrier();   // BAR2: tile t+1 resident
}

template<int OUT_BF16, int RELU>
__global__ __launch_bounds__(512, 2) void gemm_bt_256(
    const unsigned short* __restrict__ A,   // [M][K] bf16
    const unsigned short* __restrict__ Bt,  // [N][K] bf16
    const float* __restrict__ bias,         // [N] fp32
    void* __restrict__ C0, void* __restrict__ C1, int Msplit,
    int M, int N, int K)
{
  __shared__ unsigned short As[2][16384];   // 2 x 256x64 bf16 = 64 KB
  __shared__ unsigned short Bs[2][16384];   // 64 KB

  const int tid  = threadIdx.x;
  const int wave = tid >> 6;
  const int lane = tid & 63;

  // L2 block swizzle (m-panels of 256 rows), GROUP_M=8 (R4-verified)
  const int nbx = N >> 8;
  const int gsize = nbx * GROUP_M;
  const int grp = blockIdx.x / gsize, within = blockIdx.x % gsize;
  const int m0 = (grp * GROUP_M + (within % GROUP_M)) << 8;
  const int n0 = (within / GROUP_M) << 8;

  const int wm = (wave >> 2) << 7;   // 0 / 128
  const int wn = (wave & 3) << 6;    // 0 / 64 / 128 / 192

  // staging lane geometry: call = 512 lanes x 16B = 64 rows x 128B (one chunk)
  const int srow   = tid >> 3;                  // row within chunk (0..63)
  const int schunk = (tid & 7) ^ (srow & 7);    // pre-swizzled 16B chunk
  const unsigned short* gA = A  + (size_t)(m0 + srow) * K + schunk * 8;
  const unsigned short* gB = Bt + (size_t)(n0 + srow) * K + schunk * 8;
  const int ldst = wave << 9;                   // wave-uniform LDS slice (ushorts)

  // fragment read geometry (16x16x32: lane holds k = q*8..q*8+7 of row fr)
  const int fr = lane & 15, q = lane >> 4;
  const int sw0 = (q << 3) ^ ((fr & 7) << 3);   // ks=0 swizzled col offset
  const int sw1 = sw0 ^ 32;                     // ks=1
  const int abase = (wm + fr) << 6;
  const int bbase = (wn + fr) << 6;

  f32x4 acc[8][4] = {};
  FragSet fE, fO;

  unsigned short* A0p = &As[0][0]; unsigned short* B0p = &Bs[0][0];
  unsigned short* A1p = &As[1][0]; unsigned short* B1p = &Bs[1][0];

  // prologue: tile0 full (8 calls) + tile1 partial {A c0,c2; B c0..c3};
  // vmcnt(6) -> tile0 resident, 6 outstanding = tile1 partial (invariant).
  async16(gA,                        A0p + ldst);
  async16(gA + (size_t)64 * K,       A0p + 4096 + ldst);
  async16(gA + (size_t)128 * K,      A0p + 8192 + ldst);
  async16(gA + (size_t)192 * K,      A0p + 12288 + ldst);
  async16(gB,                        B0p + ldst);
  async16(gB + (size_t)64 * K,       B0p + 4096 + ldst);
  async16(gB + (size_t)128 * K,      B0p + 8192 + ldst);
  async16(gB + (size_t)192 * K,      B0p + 12288 + ldst);
  async16(gA + 64,                   A1p + ldst);
  async16(gA + (size_t)128 * K + 64, A1p + 8192 + ldst);
  async16(gB + 64,                   B1p + ldst);
  async16(gB + (size_t)64 * K + 64,  B1p + 4096 + ldst);
  async16(gB + (size_t)128 * K + 64, B1p + 8192 + ldst);
  async16(gB + (size_t)192 * K + 64, B1p + 12288 + ldst);
  asm volatile("s_waitcnt vmcnt(6)" ::: "memory");
  __builtin_amdgcn_s_barrier();

  const int NT = K >> 6;   // 16 (GEMM1) or 32 (GEMM2); even, >= 6

  // t = 0 (E): q1/q2 only (q3/q4 run inside iter t=1), full staging
  ktile<false, true, true, true, 6, true>(fE, fE, A0p, B0p, A1p, gA, gB, K,
      64, 128, ldst, abase, bbase, sw0, sw1, acc);

  // t = 1 .. NT-4 in pairs (full tiles 1..NT-4); NT-3 peeled below
#pragma unroll 1
  for (int t = 1; t <= NT - 5; t += 2) {
    ktile<true, true, true, true, 6, true>(fO, fE, A1p, B1p, A0p, gA, gB, K,
        (t + 1) << 6, (t + 2) << 6, ldst, abase, bbase, sw0, sw1, acc);
    ktile<true, true, true, true, 6, true>(fE, fO, A0p, B0p, A1p, gA, gB, K,
        (t + 2) << 6, (t + 3) << 6, ldst, abase, bbase, sw0, sw1, acc);
  }
  // t = NT-3 (odd -> O), full
  ktile<true, true, true, true, 6, true>(fO, fE, A1p, B1p, A0p, gA, gB, K,
      (NT - 2) << 6, (NT - 1) << 6, ldst, abase, bbase, sw0, sw1, acc);
  // t = NT-2 (even -> E): no S2; vmcnt(0) (outstanding = S2@NT-3 + S1@NT-2 = 8)
  ktile<true, true, true, false, 0, true>(fE, fO, A0p, B0p, A1p, gA, gB, K,
      (NT - 1) << 6, 0, ldst, abase, bbase, sw0, sw1, acc);
  // t = NT-1 (odd -> O): no staging, no barriers
  ktile<true, true, false, false, -1, false>(fO, fE, A1p, B1p, A0p, gA, gB, K,
      0, 0, ldst, abase, bbase, sw0, sw1, acc);
  // tail: q3/q4 of tile NT-1
  ktile<true, false, false, false, -1, false>(fE, fO, A1p, B1p, A0p, gA, gB, K,
      0, 0, ldst, abase, bbase, sw0, sw1, acc);

  // epilogue: bias + optional relu; per-block output select (tile-aligned)
  // C/D layout: col = lane&15, row = (lane>>4)*4 + reg   [m89/m91 verified]
  // j INNERMOST: each 128B output line completed in 4 consecutive stores
  // (R2-verified: WRITE_SIZE == output size).
  void* Cb = (m0 < Msplit) ? C0 : C1;
  const int mbase = (m0 < Msplit) ? m0 : (m0 - Msplit);
  const int crow = mbase + wm + (lane >> 4) * 4;
  const int ccol = n0 + wn + (lane & 15);
  float bv[4];
#pragma unroll
  for (int j = 0; j < 4; ++j) bv[j] = bias[ccol + j * 16];
#pragma unroll
  for (int i = 0; i < 8; ++i) {
#pragma unroll
    for (int r = 0; r < 4; ++r) {
      size_t base = (size_t)(crow + i * 16 + r) * N + ccol;
#pragma unroll
      for (int j = 0; j < 4; ++j) {
        float v = acc[i][j][r] + bv[j];
        if (RELU) v = fmaxf(v, 0.0f);
        if (OUT_BF16) ((unsigned short*)Cb)[base + j * 16] = f2bf(v);
        else          ((float*)Cb)[base + j * 16] = v;
      }
    }
  }
}

// ---------------------------------------------------------------------------
// post_kernel: comb (blocks [0, SUNL/2)) + yhat (blocks [SUNL/2, +SLAB/4))
// ---------------------------------------------------------------------------
#define COMB_BLOCKS (SUNL / 2)              // 8192
#define YHAT_BLOCKS (SLAB / 4)              // 2048
#define POST_BLOCKS (COMB_BLOCKS + YHAT_BLOCKS)

__global__ __launch_bounds__(256) void post_kernel(
    const float* __restrict__ feat_l, const float* __restrict__ W3,
    const float* __restrict__ b3, const int* __restrict__ ia,
    const int* __restrict__ ib, const float* __restrict__ kv,
    float* __restrict__ out_comb, float* __restrict__ out_yhat)
{
  int b = blockIdx.x;
  if (b < COMB_BLOCKS) {
    int row = b * 2 + (threadIdx.x >> 7);
    int c = (threadIdx.x & 127) << 2;
    float k = kv[row];
    float km1 = 1.0f - k;
    float4 fa = *(const float4*)(feat_l + (size_t)ia[row] * HID2 + c);
    float4 fb = *(const float4*)(feat_l + (size_t)ib[row] * HID2 + c);
    float4 o;
    o.x = k * fa.x + km1 * fb.x;
    o.y = k * fa.y + km1 * fb.y;
    o.z = k * fa.z + km1 * fb.z;
    o.w = k * fa.w + km1 * fb.w;
    *(float4*)(out_comb + (size_t)row * HID2 + c) = o;
  } else {
    int wave = threadIdx.x >> 6;
    int lane = threadIdx.x & 63;
    int row = (b - COMB_BLOCKS) * 4 + wave;
    const float* f = feat_l + (size_t)row * HID2;
    float s = 0.f;
#pragma unroll
    for (int j = 0; j < HID2 / 64; ++j) s = fmaf(f[lane + j * 64], W3[lane + j * 64], s);
#pragma unroll
    for (int off = 32; off; off >>= 1) s += __shfl_down(s, off);
    if (lane == 0) out_yhat[row] = s + b3[0];
  }
}

// ---------------------------------------------------------------------------
extern "C" void kernel_launch(void* const* d_in, const int* in_sizes, int n_in,
                              void* d_out, int out_size, void* d_ws, size_t ws_size,
                              hipStream_t stream)
{
  const float* X_l = (const float*)d_in[0];
  const float* y_l = (const float*)d_in[1];
  const float* X_u = (const float*)d_in[2];
  const float* y_u = (const float*)d_in[3];
  const float* W1  = (const float*)d_in[4];
  const float* b1  = (const float*)d_in[5];
  const float* W2  = (const float*)d_in[6];
  const float* b2  = (const float*)d_in[7];
  const float* W3  = (const float*)d_in[8];
  const float* b3  = (const float*)d_in[9];

  float* out_featu = (float*)d_out;
  float* out_comb  = out_featu + (size_t)SUNL * HID2;
  float* out_yhat  = out_comb + (size_t)SUNL * HID2;

  // Workspace (~174 MB): X_bf = [Xl|Xu] contig, H_bf = [Hl|Hu] contig
  unsigned short* X_bf  = (unsigned short*)d_ws;                 // [24576][1024]
  unsigned short* W1T   = X_bf + (size_t)MTOT * DIMX;
  unsigned short* W2T   = W1T + (size_t)HID1 * DIMX;
  unsigned short* H_bf  = W2T + (size_t)HID2 * HID1;             // [24576][2048]
  float* feat_l = (float*)(H_bf + (size_t)MTOT * HID1);
  int*   ai = (int*)(feat_l + (size_t)SLAB * HID2);
  int*   bi = ai + SUNL;
  float* kv = (float*)(bi + SUNL);

  prep_kernel<<<dim3(PREP_BLOCKS), dim3(256), 0, stream>>>(
      X_l, X_u, W1, W2, y_l, y_u, X_bf, W1T, W2T, ai, bi, kv);

  // layer 1 (merged l+u): H = relu(X @ W1 + b1) -> bf16  [768 blocks x 512]
  gemm_bt_256<1, 1><<<dim3((HID1 / 256) * (MTOT / 256)), dim3(512), 0, stream>>>(
      X_bf, W1T, b1, H_bf, H_bf, MTOT /*no split*/, MTOT, HID1, DIMX);

  // layer 2 (merged l+u): feat = relu(H @ W2 + b2) -> fp32, split dest [192 blocks]
  gemm_bt_256<0, 1><<<dim3((HID2 / 256) * (MTOT / 256)), dim3(512), 0, stream>>>(
      H_bf, W2T, b2, feat_l, out_featu, SLAB, MTOT, HID2, HID1);

  post_kernel<<<dim3(POST_BLOCKS), dim3(256), 0, stream>>>(
      feat_l, W3, b3, ai, bi, kv, out_comb, out_yhat);
}

// Round 4
// 426.915 us; speedup vs baseline: 1.5064x; 1.5064x over previous
//
#include <hip/hip_runtime.h>
#include <stdint.h>

// Problem constants (match reference)
#define SLAB 8192    // SL
#define SUNL 16384   // SU
#define DIMX 1024
#define HID1 2048
#define HID2 512
#define KTRIES 8
#define MTOT (SLAB + SUNL)   // 24576

typedef __attribute__((ext_vector_type(8))) short bf16x8;    // 8 bf16 = 4 VGPRs
typedef __attribute__((ext_vector_type(4))) float f32x4;

// fp32 -> bf16 round-to-nearest-even
__device__ __forceinline__ unsigned short f2bf(float f) {
  union { float f; uint32_t u; } c; c.f = f;
  return (unsigned short)((c.u + 0x7fffu + ((c.u >> 16) & 1u)) >> 16);
}

// async global->LDS, 16B per lane; lds dest = wave-uniform base + lane*16
__device__ __forceinline__ void async16(const void* g, void* l) {
  __builtin_amdgcn_global_load_lds(
      (const __attribute__((address_space(1))) unsigned int*)g,
      (__attribute__((address_space(3))) unsigned int*)l,
      16, 0, 0);
}

// ---------------------------------------------------------------------------
// Threefry2x32 (JAX-compatible, 20 rounds)
// ---------------------------------------------------------------------------
struct U2 { uint32_t x, y; };

__device__ __forceinline__ U2 threefry(uint32_t k0, uint32_t k1, uint32_t x0, uint32_t x1) {
  uint32_t ks2 = k0 ^ k1 ^ 0x1BD11BDAu;
  x0 += k0; x1 += k1;
#define TF_R(r) { x0 += x1; x1 = (x1 << (r)) | (x1 >> (32 - (r))); x1 ^= x0; }
  TF_R(13) TF_R(15) TF_R(26) TF_R(6)
  x0 += k1; x1 += ks2 + 1u;
  TF_R(17) TF_R(29) TF_R(16) TF_R(24)
  x0 += ks2; x1 += k0 + 2u;
  TF_R(13) TF_R(15) TF_R(26) TF_R(6)
  x0 += k0; x1 += k1 + 3u;
  TF_R(17) TF_R(29) TF_R(16) TF_R(24)
  x0 += k1; x1 += ks2 + 4u;
  TF_R(13) TF_R(15) TF_R(26) TF_R(6)
  x0 += ks2; x1 += k0 + 5u;
#undef TF_R
  return {x0, x1};
}

// ---------------------------------------------------------------------------
// prep_kernel: one launch for cast(X_l|X_u), transpose-cast W1, W2, and pairs.
// ---------------------------------------------------------------------------
#define XL_BLOCKS (SLAB * DIMX / 4 / 256)           // 8192
#define CAST_BLOCKS (MTOT * DIMX / 4 / 256)         // 24576
#define T1_NBX (HID1 / 32)                          // 64
#define T1_BLOCKS ((HID1 / 32) * (DIMX / 32))       // 2048
#define T2_NBX (HID2 / 32)                          // 16
#define T2_BLOCKS ((HID2 / 32) * (HID1 / 32))       // 1024
#define PAIR_BLOCKS (SUNL / 256)                    // 64
#define PREP_BLOCKS (CAST_BLOCKS + T1_BLOCKS + T2_BLOCKS + PAIR_BLOCKS)

__global__ __launch_bounds__(256) void prep_kernel(
    const float* __restrict__ Xl, const float* __restrict__ Xu,
    const float* __restrict__ W1, const float* __restrict__ W2,
    const float* __restrict__ y_l, const float* __restrict__ y_u,
    unsigned short* __restrict__ X_bf, unsigned short* __restrict__ W1T,
    unsigned short* __restrict__ W2T,
    int* __restrict__ ia, int* __restrict__ ib, float* __restrict__ kv)
{
  __shared__ float t[32][33];
  int b = blockIdx.x;
  int tid = threadIdx.x;

  if (b < CAST_BLOCKS) {
    const float* src; size_t i, doff;
    if (b < XL_BLOCKS) { src = Xl; i = (size_t)b * 256 + tid; doff = 0; }
    else { src = Xu; i = (size_t)(b - XL_BLOCKS) * 256 + tid; doff = (size_t)SLAB * DIMX / 4; }
    float4 v = ((const float4*)src)[i];
    ushort4 o;
    o.x = f2bf(v.x); o.y = f2bf(v.y); o.z = f2bf(v.z); o.w = f2bf(v.w);
    ((ushort4*)X_bf)[doff + i] = o;
  } else if (b < CAST_BLOCKS + T1_BLOCKS + T2_BLOCKS) {
    const float* W; unsigned short* WT; int K, N, bx, by;
    if (b < CAST_BLOCKS + T1_BLOCKS) {
      int tb = b - CAST_BLOCKS;
      W = W1; WT = W1T; K = DIMX; N = HID1; bx = tb % T1_NBX; by = tb / T1_NBX;
    } else {
      int tb = b - CAST_BLOCKS - T1_BLOCKS;
      W = W2; WT = W2T; K = HID1; N = HID2; bx = tb % T2_NBX; by = tb / T2_NBX;
    }
    int k0 = by * 32, n0 = bx * 32;
    int tx = tid & 31, ty = tid >> 5;
#pragma unroll
    for (int i = 0; i < 32; i += 8)
      t[ty + i][tx] = W[(size_t)(k0 + ty + i) * N + n0 + tx];
    __syncthreads();
#pragma unroll
    for (int i = 0; i < 32; i += 8)
      WT[(size_t)(n0 + ty + i) * K + k0 + tx] = f2bf(t[tx][ty + i]);
  } else {
    // pair sampling (verified R1: partitionable threefry, bits1^bits2, &8191)
    int r = (b - CAST_BLOCKS - T1_BLOCKS - T2_BLOCKS) * 256 + tid;
    U2 ka  = threefry(0u, 42u, 0u, 0u);
    U2 kb  = threefry(0u, 42u, 0u, 1u);
    U2 k2a = threefry(ka.x, ka.y, 0u, 1u);
    U2 k2b = threefry(kb.x, kb.y, 0u, 1u);
    int iav[KTRIES], ibv[KTRIES];
#pragma unroll
    for (int c = 0; c < KTRIES; ++c) {
      uint32_t tt = (uint32_t)(r * KTRIES + c);
      U2 oa = threefry(k2a.x, k2a.y, 0u, tt);
      U2 ob = threefry(k2b.x, k2b.y, 0u, tt);
      iav[c] = (int)((oa.x ^ oa.y) & (SLAB - 1));
      ibv[c] = (int)((ob.x ^ ob.y) & (SLAB - 1));
    }
    int a = iav[0], bb2 = ibv[0];
#pragma unroll
    for (int c = 0; c < KTRIES; ++c) {
      if (iav[c] != ibv[c] && y_l[iav[c]] != y_l[ibv[c]]) { a = iav[c]; bb2 = ibv[c]; break; }
    }
    float ya = y_l[a], yb = y_l[bb2];
    ia[r] = a; ib[r] = bb2; kv[r] = (y_u[r] - yb) / (ya - yb);
  }
}

// ---------------------------------------------------------------------------
// bf16 MFMA GEMM, 256x256 tile, BK=64, ONE-QUADRANT cross-tile rotation (R4):
//   - 512 threads = 8 waves (2M x 4N); wave tile 128x64 = 8x4 of 16x16x32.
//     LDS 128 KB double-buffer -> 1 block/CU (2 waves/SIMD) -> 256-reg cap
//     TOTAL (VGPR+AGPR unified). acc = 128 AGPR; so frag VGPR peak must
//     stay ~<=128. R3 carried 2 full FragSets (192) -> silent spill
//     (FETCH 249 MB / WRITE 538 MB). R4 defers ONLY q4 (a1 x b1): at the
//     overlap point live = of.a1/b1 (48) + nf.a0/b0 (48) + addr (~30) =
//     ~126 VGPR + 128 AGPR = 254 <= 256.
//   - Per-tile schedule (2 barriers, counted in-order waits):
//       A:  issue a0(8)+b0(4) ds_reads [cur] | S1(2) [other]
//       B:  q4'(t-1) = of.a1 x of.b1, 16 MFMA (pure register)  <- overlaps
//           the a0/b0 LDS drain (R2's exposed tile-head stall)
//       B2: issue b1(4)+a1(8) ds_reads [cur]   <- drain overlaps q1/q2
//       C:  lgkm(12) q1=a0xb0   D: lgkm(8) q2=a0xb1   F: lgkm(0) BAR1
//       G:  S2(6) [cur <- t+2]  H: q3=a1xb0   I: vmcnt(6) BAR2
//     DS completes in order per wave -> lgkm counts exact (24 issued:
//     12 left = a0+b0 done; 8 left = +b1; 0 = all).
//   - Hazards: S1@t (A c1,c3 of t+1 -> other buf): other-buf a1 reads
//     (c1/c3) DS-complete at lgkm(0) before BAR1@t-1 < BAR2@t-1 < S1@t.
//     S2@t (cur buf): after BAR1@t, all cur reads drained. q3 (c1/c3)
//     runs concurrent with S2 writes (c0/c2 + B) - disjoint regions.
//   - vmcnt ledger (= R2, verified): at vmcnt(6)@t outstanding =
//     S2@t-1(6) + S1@t(2) + S2@t(6) = 14 -> drains oldest 8 = tile t+1
//     fully resident at BAR2. Prologue: tile0(8) + tile1-partial(6),
//     vmcnt(6) = tile0 resident. Tail: vmcnt(0) at t=NT-2.
//   - Per-acc-element K accumulation order unchanged (q4 of tile t
//     executes at iter t+1 but still in increasing-t order per element)
//     -> bit-identical output vs R2 (passed, absmax 144).
//   - XOR swizzle (T2) unchanged: 0 bank conflicts measured.
//   - Epilogue j-innermost (R2-verified: WRITE_SIZE == output size).
// ---------------------------------------------------------------------------
#define GROUP_M 8
#define MFMA_B16(a, b, c) __builtin_amdgcn_mfma_f32_16x16x32_bf16(a, b, c, 0, 0, 0)
#define SBAR __builtin_amdgcn_sched_barrier(0)

struct FragSet { bf16x8 a0[4][2], a1[4][2], b0[2][2], b1[2][2]; };

template<bool Q4P, bool M1, bool S1F, bool S2F, int VMC, bool BARS>
__device__ __forceinline__ void ktile(
    FragSet& nf, FragSet& of,
    unsigned short* Ac, unsigned short* Bc, unsigned short* Ao,
    const unsigned short* gA, const unsigned short* gB,
    int K, int k1, int k2, int ldst,
    int abase, int bbase, int sw0, int sw1,
    f32x4 (&acc)[8][4])
{
  if (M1) {  // phase A: a0(8) + b0(4) reads from cur
#pragma unroll
    for (int i = 0; i < 4; ++i) {
      nf.a0[i][0] = *(const bf16x8*)(Ac + abase + i * 1024 + sw0);
      nf.a0[i][1] = *(const bf16x8*)(Ac + abase + i * 1024 + sw1);
    }
#pragma unroll
    for (int j = 0; j < 2; ++j) {
      nf.b0[j][0] = *(const bf16x8*)(Bc + bbase + j * 1024 + sw0);
      nf.b0[j][1] = *(const bf16x8*)(Bc + bbase + j * 1024 + sw1);
    }
    SBAR;
  }
  if (S1F) {  // stage A c1,c3 of t+1 -> other buf
    async16(gA + (size_t)64 * K + k1,  Ao + 4096 + ldst);
    async16(gA + (size_t)192 * K + k1, Ao + 12288 + ldst);
    SBAR;
  }
  if (Q4P) {  // phase B: q4(t-1) = old a1 x old b1, pure register
    __builtin_amdgcn_s_setprio(1);
#pragma unroll
    for (int i = 0; i < 4; ++i)
#pragma unroll
      for (int j = 0; j < 2; ++j) {
        acc[i + 4][j + 2] = MFMA_B16(of.a1[i][0], of.b1[j][0], acc[i + 4][j + 2]);
        acc[i + 4][j + 2] = MFMA_B16(of.a1[i][1], of.b1[j][1], acc[i + 4][j + 2]);
      }
    __builtin_amdgcn_s_setprio(0);
    SBAR;
  }
  if (M1) {
    // phase B2: b1(4) + a1(8) reads (after q4' so old/new frag sets
    // never fully coexist -> no spill)
#pragma unroll
    for (int j = 0; j < 2; ++j) {
      nf.b1[j][0] = *(const bf16x8*)(Bc + bbase + (j + 2) * 1024 + sw0);
      nf.b1[j][1] = *(const bf16x8*)(Bc + bbase + (j + 2) * 1024 + sw1);
    }
#pragma unroll
    for (int i = 0; i < 4; ++i) {
      nf.a1[i][0] = *(const bf16x8*)(Ac + abase + (i + 4) * 1024 + sw0);
      nf.a1[i][1] = *(const bf16x8*)(Ac + abase + (i + 4) * 1024 + sw1);
    }
    SBAR;
    // q1: a0 x b0  (needs first 12 of 24 reads)
    asm volatile("s_waitcnt lgkmcnt(12)" ::: "memory");
    SBAR;
    __builtin_amdgcn_s_setprio(1);
#pragma unroll
    for (int i = 0; i < 4; ++i)
#pragma unroll
      for (int j = 0; j < 2; ++j) {
        acc[i][j] = MFMA_B16(nf.a0[i][0], nf.b0[j][0], acc[i][j]);
        acc[i][j] = MFMA_B16(nf.a0[i][1], nf.b0[j][1], acc[i][j]);
      }
    __builtin_amdgcn_s_setprio(0);
    // q2: a0 x b1  (needs first 16)
    asm volatile("s_waitcnt lgkmcnt(8)" ::: "memory");
    SBAR;
    __builtin_amdgcn_s_setprio(1);
#pragma unroll
    for (int i = 0; i < 4; ++i)
#pragma unroll
      for (int j = 0; j < 2; ++j) {
        acc[i][j + 2] = MFMA_B16(nf.a0[i][0], nf.b1[j][0], acc[i][j + 2]);
        acc[i][j + 2] = MFMA_B16(nf.a0[i][1], nf.b1[j][1], acc[i][j + 2]);
      }
    __builtin_amdgcn_s_setprio(0);
    asm volatile("s_waitcnt lgkmcnt(0)" ::: "memory");
    SBAR;
  }
  if (BARS) __builtin_amdgcn_s_barrier();   // BAR1: all cur reads drained
  if (S2F) {  // stage A c0,c2 + B c0..c3 of t+2 -> cur buf
    async16(gA + k2,                   Ac + ldst);
    async16(gA + (size_t)128 * K + k2, Ac + 8192 + ldst);
    async16(gB + k2,                   Bc + ldst);
    async16(gB + (size_t)64 * K + k2,  Bc + 4096 + ldst);
    async16(gB + (size_t)128 * K + k2, Bc + 8192 + ldst);
    async16(gB + (size_t)192 * K + k2, Bc + 12288 + ldst);
    SBAR;
  }
  if (M1) {
    // q3: a1 x b0 (reads complete; overlaps S2's issue + DMA landing)
    __builtin_amdgcn_s_setprio(1);
#pragma unroll
    for (int i = 0; i < 4; ++i)
#pragma unroll
      for (int j = 0; j < 2; ++j) {
        acc[i + 4][j] = MFMA_B16(nf.a1[i][0], nf.b0[j][0], acc[i + 4][j]);
        acc[i + 4][j] = MFMA_B16(nf.a1[i][1], nf.b0[j][1], acc[i + 4][j]);
      }
    __builtin_amdgcn_s_setprio(0);
  }
  if (VMC == 6)      asm volatile("s_waitcnt vmcnt(6)" ::: "memory");
  else if (VMC == 0) asm volatile("s_waitcnt vmcnt(0)" ::: "memory");
  if (BARS) __builtin_amdgcn_s_barrier();   // BAR2: tile t+1 resident
}

template<int OUT_BF16, int RELU>
__global__ __launch_bounds__(512, 2) void gemm_bt_256(
    const unsigned short* __restrict__ A,   // [M][K] bf16
    const unsigned short* __restrict__ Bt,  // [N][K] bf16
    const float* __restrict__ bias,         // [N] fp32
    void* __restrict__ C0, void* __restrict__ C1, int Msplit,
    int M, int N, int K)
{
  __shared__ unsigned short As[2][16384];   // 2 x 256x64 bf16 = 64 KB
  __shared__ unsigned short Bs[2][16384];   // 64 KB

  const int tid  = threadIdx.x;
  const int wave = tid >> 6;
  const int lane = tid & 63;

  // L2 block swizzle (m-panels of 256 rows), GROUP_M=8 (R4-verified)
  const int nbx = N >> 8;
  const int gsize = nbx * GROUP_M;
  const int grp = blockIdx.x / gsize, within = blockIdx.x % gsize;
  const int m0 = (grp * GROUP_M + (within % GROUP_M)) << 8;
  const int n0 = (within / GROUP_M) << 8;

  const int wm = (wave >> 2) << 7;   // 0 / 128
  const int wn = (wave & 3) << 6;    // 0 / 64 / 128 / 192

  // staging lane geometry: call = 512 lanes x 16B = 64 rows x 128B (one chunk)
  const int srow   = tid >> 3;                  // row within chunk (0..63)
  const int schunk = (tid & 7) ^ (srow & 7);    // pre-swizzled 16B chunk
  const unsigned short* gA = A  + (size_t)(m0 + srow) * K + schunk * 8;
  const unsigned short* gB = Bt + (size_t)(n0 + srow) * K + schunk * 8;
  const int ldst = wave << 9;                   // wave-uniform LDS slice (ushorts)

  // fragment read geometry (16x16x32: lane holds k = q*8..q*8+7 of row fr)
  const int fr = lane & 15, q = lane >> 4;
  const int sw0 = (q << 3) ^ ((fr & 7) << 3);   // ks=0 swizzled col offset
  const int sw1 = sw0 ^ 32;                     // ks=1
  const int abase = (wm + fr) << 6;
  const int bbase = (wn + fr) << 6;

  f32x4 acc[8][4] = {};
  FragSet fE, fO;

  unsigned short* A0p = &As[0][0]; unsigned short* B0p = &Bs[0][0];
  unsigned short* A1p = &As[1][0]; unsigned short* B1p = &Bs[1][0];

  // prologue: tile0 full (8 calls) + tile1 partial {A c0,c2; B c0..c3};
  // vmcnt(6) -> tile0 resident, 6 outstanding = tile1 partial (invariant).
  async16(gA,                        A0p + ldst);
  async16(gA + (size_t)64 * K,       A0p + 4096 + ldst);
  async16(gA + (size_t)128 * K,      A0p + 8192 + ldst);
  async16(gA + (size_t)192 * K,      A0p + 12288 + ldst);
  async16(gB,                        B0p + ldst);
  async16(gB + (size_t)64 * K,       B0p + 4096 + ldst);
  async16(gB + (size_t)128 * K,      B0p + 8192 + ldst);
  async16(gB + (size_t)192 * K,      B0p + 12288 + ldst);
  async16(gA + 64,                   A1p + ldst);
  async16(gA + (size_t)128 * K + 64, A1p + 8192 + ldst);
  async16(gB + 64,                   B1p + ldst);
  async16(gB + (size_t)64 * K + 64,  B1p + 4096 + ldst);
  async16(gB + (size_t)128 * K + 64, B1p + 8192 + ldst);
  async16(gB + (size_t)192 * K + 64, B1p + 12288 + ldst);
  asm volatile("s_waitcnt vmcnt(6)" ::: "memory");
  __builtin_amdgcn_s_barrier();

  const int NT = K >> 6;   // 16 (GEMM1) or 32 (GEMM2); even, >= 6

  // t = 0 (E): no deferred quadrant yet
  ktile<false, true, true, true, 6, true>(fE, fO, A0p, B0p, A1p, gA, gB, K,
      64, 128, ldst, abase, bbase, sw0, sw1, acc);

  // t = 1 .. NT-4 in pairs
#pragma unroll 1
  for (int t = 1; t <= NT - 5; t += 2) {
    ktile<true, true, true, true, 6, true>(fO, fE, A1p, B1p, A0p, gA, gB, K,
        (t + 1) << 6, (t + 2) << 6, ldst, abase, bbase, sw0, sw1, acc);
    ktile<true, true, true, true, 6, true>(fE, fO, A0p, B0p, A1p, gA, gB, K,
        (t + 2) << 6, (t + 3) << 6, ldst, abase, bbase, sw0, sw1, acc);
  }
  // t = NT-3 (odd -> O), full
  ktile<true, true, true, true, 6, true>(fO, fE, A1p, B1p, A0p, gA, gB, K,
      (NT - 2) << 6, (NT - 1) << 6, ldst, abase, bbase, sw0, sw1, acc);
  // t = NT-2 (even -> E): S1 stages tile NT-1 c1,c3; no S2; vmcnt(0)
  ktile<true, true, true, false, 0, true>(fE, fO, A0p, B0p, A1p, gA, gB, K,
      (NT - 1) << 6, 0, ldst, abase, bbase, sw0, sw1, acc);
  // t = NT-1 (odd -> O): no staging, no barriers
  ktile<true, true, false, false, -1, false>(fO, fE, A1p, B1p, A0p, gA, gB, K,
      0, 0, ldst, abase, bbase, sw0, sw1, acc);
  // tail: q4 of tile NT-1 (frags in fO)
  ktile<true, false, false, false, -1, false>(fE, fO, A1p, B1p, A0p, gA, gB, K,
      0, 0, ldst, abase, bbase, sw0, sw1, acc);

  // epilogue: bias + optional relu; per-block output select (tile-aligned)
  // C/D layout: col = lane&15, row = (lane>>4)*4 + reg   [m89/m91 verified]
  // j INNERMOST: each 128B output line completed in 4 consecutive stores
  // (R2-verified: WRITE_SIZE == output size).
  void* Cb = (m0 < Msplit) ? C0 : C1;
  const int mbase = (m0 < Msplit) ? m0 : (m0 - Msplit);
  const int crow = mbase + wm + (lane >> 4) * 4;
  const int ccol = n0 + wn + (lane & 15);
  float bv[4];
#pragma unroll
  for (int j = 0; j < 4; ++j) bv[j] = bias[ccol + j * 16];
#pragma unroll
  for (int i = 0; i < 8; ++i) {
#pragma unroll
    for (int r = 0; r < 4; ++r) {
      size_t base = (size_t)(crow + i * 16 + r) * N + ccol;
#pragma unroll
      for (int j = 0; j < 4; ++j) {
        float v = acc[i][j][r] + bv[j];
        if (RELU) v = fmaxf(v, 0.0f);
        if (OUT_BF16) ((unsigned short*)Cb)[base + j * 16] = f2bf(v);
        else          ((float*)Cb)[base + j * 16] = v;
      }
    }
  }
}

// ---------------------------------------------------------------------------
// post_kernel: comb (blocks [0, SUNL/2)) + yhat (blocks [SUNL/2, +SLAB/4))
// ---------------------------------------------------------------------------
#define COMB_BLOCKS (SUNL / 2)              // 8192
#define YHAT_BLOCKS (SLAB / 4)              // 2048
#define POST_BLOCKS (COMB_BLOCKS + YHAT_BLOCKS)

__global__ __launch_bounds__(256) void post_kernel(
    const float* __restrict__ feat_l, const float* __restrict__ W3,
    const float* __restrict__ b3, const int* __restrict__ ia,
    const int* __restrict__ ib, const float* __restrict__ kv,
    float* __restrict__ out_comb, float* __restrict__ out_yhat)
{
  int b = blockIdx.x;
  if (b < COMB_BLOCKS) {
    int row = b * 2 + (threadIdx.x >> 7);
    int c = (threadIdx.x & 127) << 2;
    float k = kv[row];
    float km1 = 1.0f - k;
    float4 fa = *(const float4*)(feat_l + (size_t)ia[row] * HID2 + c);
    float4 fb = *(const float4*)(feat_l + (size_t)ib[row] * HID2 + c);
    float4 o;
    o.x = k * fa.x + km1 * fb.x;
    o.y = k * fa.y + km1 * fb.y;
    o.z = k * fa.z + km1 * fb.z;
    o.w = k * fa.w + km1 * fb.w;
    *(float4*)(out_comb + (size_t)row * HID2 + c) = o;
  } else {
    int wave = threadIdx.x >> 6;
    int lane = threadIdx.x & 63;
    int row = (b - COMB_BLOCKS) * 4 + wave;
    const float* f = feat_l + (size_t)row * HID2;
    float s = 0.f;
#pragma unroll
    for (int j = 0; j < HID2 / 64; ++j) s = fmaf(f[lane + j * 64], W3[lane + j * 64], s);
#pragma unroll
    for (int off = 32; off; off >>= 1) s += __shfl_down(s, off);
    if (lane == 0) out_yhat[row] = s + b3[0];
  }
}

// ---------------------------------------------------------------------------
extern "C" void kernel_launch(void* const* d_in, const int* in_sizes, int n_in,
                              void* d_out, int out_size, void* d_ws, size_t ws_size,
                              hipStream_t stream)
{
  const float* X_l = (const float*)d_in[0];
  const float* y_l = (const float*)d_in[1];
  const float* X_u = (const float*)d_in[2];
  const float* y_u = (const float*)d_in[3];
  const float* W1  = (const float*)d_in[4];
  const float* b1  = (const float*)d_in[5];
  const float* W2  = (const float*)d_in[6];
  const float* b2  = (const float*)d_in[7];
  const float* W3  = (const float*)d_in[8];
  const float* b3  = (const float*)d_in[9];

  float* out_featu = (float*)d_out;
  float* out_comb  = out_featu + (size_t)SUNL * HID2;
  float* out_yhat  = out_comb + (size_t)SUNL * HID2;

  // Workspace (~174 MB): X_bf = [Xl|Xu] contig, H_bf = [Hl|Hu] contig
  unsigned short* X_bf  = (unsigned short*)d_ws;                 // [24576][1024]
  unsigned short* W1T   = X_bf + (size_t)MTOT * DIMX;
  unsigned short* W2T   = W1T + (size_t)HID1 * DIMX;
  unsigned short* H_bf  = W2T + (size_t)HID2 * HID1;             // [24576][2048]
  float* feat_l = (float*)(H_bf + (size_t)MTOT * HID1);
  int*   ai = (int*)(feat_l + (size_t)SLAB * HID2);
  int*   bi = ai + SUNL;
  float* kv = (float*)(bi + SUNL);

  prep_kernel<<<dim3(PREP_BLOCKS), dim3(256), 0, stream>>>(
      X_l, X_u, W1, W2, y_l, y_u, X_bf, W1T, W2T, ai, bi, kv);

  // layer 1 (merged l+u): H = relu(X @ W1 + b1) -> bf16  [768 blocks x 512]
  gemm_bt_256<1, 1><<<dim3((HID1 / 256) * (MTOT / 256)), dim3(512), 0, stream>>>(
      X_bf, W1T, b1, H_bf, H_bf, MTOT /*no split*/, MTOT, HID1, DIMX);

  // layer 2 (merged l+u): feat = relu(H @ W2 + b2) -> fp32, split dest [192 blocks]
  gemm_bt_256<0, 1><<<dim3((HID2 / 256) * (MTOT / 256)), dim3(512), 0, stream>>>(
      H_bf, W2T, b2, feat_l, out_featu, SLAB, MTOT, HID2, HID1);

  post_kernel<<<dim3(POST_BLOCKS), dim3(256), 0, stream>>>(
      feat_l, W3, b3, ai, bi, kv, out_comb, out_yhat);
}

// Round 5
// 339.900 us; speedup vs baseline: 1.8921x; 1.2560x over previous
//
#include <hip/hip_runtime.h>
#include <stdint.h>

// Problem constants (match reference)
#define SLAB 8192    // SL
#define SUNL 16384   // SU
#define DIMX 1024
#define HID1 2048
#define HID2 512
#define KTRIES 8
#define MTOT (SLAB + SUNL)   // 24576

typedef __attribute__((ext_vector_type(8))) short bf16x8;    // 8 bf16 = 4 VGPRs
typedef __attribute__((ext_vector_type(4))) float f32x4;

// fp32 -> bf16 round-to-nearest-even
__device__ __forceinline__ unsigned short f2bf(float f) {
  union { float f; uint32_t u; } c; c.f = f;
  return (unsigned short)((c.u + 0x7fffu + ((c.u >> 16) & 1u)) >> 16);
}

// async global->LDS, 16B per lane; lds dest = wave-uniform base + lane*16
__device__ __forceinline__ void async16(const void* g, void* l) {
  __builtin_amdgcn_global_load_lds(
      (const __attribute__((address_space(1))) unsigned int*)g,
      (__attribute__((address_space(3))) unsigned int*)l,
      16, 0, 0);
}

// ---------------------------------------------------------------------------
// Threefry2x32 (JAX-compatible, 20 rounds)
// ---------------------------------------------------------------------------
struct U2 { uint32_t x, y; };

__device__ __forceinline__ U2 threefry(uint32_t k0, uint32_t k1, uint32_t x0, uint32_t x1) {
  uint32_t ks2 = k0 ^ k1 ^ 0x1BD11BDAu;
  x0 += k0; x1 += k1;
#define TF_R(r) { x0 += x1; x1 = (x1 << (r)) | (x1 >> (32 - (r))); x1 ^= x0; }
  TF_R(13) TF_R(15) TF_R(26) TF_R(6)
  x0 += k1; x1 += ks2 + 1u;
  TF_R(17) TF_R(29) TF_R(16) TF_R(24)
  x0 += ks2; x1 += k0 + 2u;
  TF_R(13) TF_R(15) TF_R(26) TF_R(6)
  x0 += k0; x1 += k1 + 3u;
  TF_R(17) TF_R(29) TF_R(16) TF_R(24)
  x0 += k1; x1 += ks2 + 4u;
  TF_R(13) TF_R(15) TF_R(26) TF_R(6)
  x0 += ks2; x1 += k0 + 5u;
#undef TF_R
  return {x0, x1};
}

// ---------------------------------------------------------------------------
// prep_kernel: one launch for cast(X_l|X_u), transpose-cast W1, W2, and pairs.
// ---------------------------------------------------------------------------
#define XL_BLOCKS (SLAB * DIMX / 4 / 256)           // 8192
#define CAST_BLOCKS (MTOT * DIMX / 4 / 256)         // 24576
#define T1_NBX (HID1 / 32)                          // 64
#define T1_BLOCKS ((HID1 / 32) * (DIMX / 32))       // 2048
#define T2_NBX (HID2 / 32)                          // 16
#define T2_BLOCKS ((HID2 / 32) * (HID1 / 32))       // 1024
#define PAIR_BLOCKS (SUNL / 256)                    // 64
#define PREP_BLOCKS (CAST_BLOCKS + T1_BLOCKS + T2_BLOCKS + PAIR_BLOCKS)

__global__ __launch_bounds__(256) void prep_kernel(
    const float* __restrict__ Xl, const float* __restrict__ Xu,
    const float* __restrict__ W1, const float* __restrict__ W2,
    const float* __restrict__ y_l, const float* __restrict__ y_u,
    unsigned short* __restrict__ X_bf, unsigned short* __restrict__ W1T,
    unsigned short* __restrict__ W2T,
    int* __restrict__ ia, int* __restrict__ ib, float* __restrict__ kv)
{
  __shared__ float t[32][33];
  int b = blockIdx.x;
  int tid = threadIdx.x;

  if (b < CAST_BLOCKS) {
    const float* src; size_t i, doff;
    if (b < XL_BLOCKS) { src = Xl; i = (size_t)b * 256 + tid; doff = 0; }
    else { src = Xu; i = (size_t)(b - XL_BLOCKS) * 256 + tid; doff = (size_t)SLAB * DIMX / 4; }
    float4 v = ((const float4*)src)[i];
    ushort4 o;
    o.x = f2bf(v.x); o.y = f2bf(v.y); o.z = f2bf(v.z); o.w = f2bf(v.w);
    ((ushort4*)X_bf)[doff + i] = o;
  } else if (b < CAST_BLOCKS + T1_BLOCKS + T2_BLOCKS) {
    const float* W; unsigned short* WT; int K, N, bx, by;
    if (b < CAST_BLOCKS + T1_BLOCKS) {
      int tb = b - CAST_BLOCKS;
      W = W1; WT = W1T; K = DIMX; N = HID1; bx = tb % T1_NBX; by = tb / T1_NBX;
    } else {
      int tb = b - CAST_BLOCKS - T1_BLOCKS;
      W = W2; WT = W2T; K = HID1; N = HID2; bx = tb % T2_NBX; by = tb / T2_NBX;
    }
    int k0 = by * 32, n0 = bx * 32;
    int tx = tid & 31, ty = tid >> 5;
#pragma unroll
    for (int i = 0; i < 32; i += 8)
      t[ty + i][tx] = W[(size_t)(k0 + ty + i) * N + n0 + tx];
    __syncthreads();
#pragma unroll
    for (int i = 0; i < 32; i += 8)
      WT[(size_t)(n0 + ty + i) * K + k0 + tx] = f2bf(t[tx][ty + i]);
  } else {
    // pair sampling (verified R1: partitionable threefry, bits1^bits2, &8191)
    int r = (b - CAST_BLOCKS - T1_BLOCKS - T2_BLOCKS) * 256 + tid;
    U2 ka  = threefry(0u, 42u, 0u, 0u);
    U2 kb  = threefry(0u, 42u, 0u, 1u);
    U2 k2a = threefry(ka.x, ka.y, 0u, 1u);
    U2 k2b = threefry(kb.x, kb.y, 0u, 1u);
    int iav[KTRIES], ibv[KTRIES];
#pragma unroll
    for (int c = 0; c < KTRIES; ++c) {
      uint32_t tt = (uint32_t)(r * KTRIES + c);
      U2 oa = threefry(k2a.x, k2a.y, 0u, tt);
      U2 ob = threefry(k2b.x, k2b.y, 0u, tt);
      iav[c] = (int)((oa.x ^ oa.y) & (SLAB - 1));
      ibv[c] = (int)((ob.x ^ ob.y) & (SLAB - 1));
    }
    int a = iav[0], bb2 = ibv[0];
#pragma unroll
    for (int c = 0; c < KTRIES; ++c) {
      if (iav[c] != ibv[c] && y_l[iav[c]] != y_l[ibv[c]]) { a = iav[c]; bb2 = ibv[c]; break; }
    }
    float ya = y_l[a], yb = y_l[bb2];
    ia[r] = a; ib[r] = bb2; kv[r] = (y_u[r] - yb) / (ya - yb);
  }
}

// ---------------------------------------------------------------------------
// bf16 MFMA GEMM, 256x256 tile, BK=32, one-quadrant rotation + pre-issued
// head reads (R5):
//   - 512 threads = 8 waves (2M x 4N); wave tile 128x64 = 8x4 of 16x16x32.
//   - REGISTER WALL (R3/R4 lesson): 256 regs/wave TOTAL (VGPR+AGPR unified),
//     acc = 128 AGPR. BK=32 halves all frag footprints: static frag pool =
//     a0 x2(32) + b0 x2(16) + a1 x2(32) + b1 x2(16) = 96 VGPR; + addr ~20
//     + acc 128 = ~244 <= 256. (R4's BK=64 pool was 144 -> spill: FETCH
//     120 MB / WRITE 261 MB.)
//   - Per tile t (quadrants of 8 MFMA; counted IN-ORDER lgkm; reads issued
//     one MFMA-cluster ahead of use):
//       entry: {a0,b0}@t outstanding (pre-issued last tile); q4(t-1) pending
//       ph1: issue b1@t(2) | q4'(t-1) x8 (reg-only, covers head drain)
//            | lgkm(2) [a0,b0 done] | q1 = a0 x b0 x8
//       ph2: issue a1@t(4) | lgkm(4) [b1 done] | q2 = a0 x b1 x8 | lgkm(0)
//       BAR1  (all cur-buf ds_reads DS-complete -> staging into cur safe)
//       ph3: stage t+2 -> cur buf (4 x global_load_lds) | q3 = a1 x b0 x8
//            | vmcnt(4) [S@t-1 landed -> tile t+1 resident] | BAR2
//       ph4: pre-issue {a0,b0}@t+1 (6 reads, NEXT buf; drain under q3/q4)
//     2 barriers/tile; q4@t runs at head of t+1 (carry = a1,b1 = 24 regs).
//   - vmcnt ledger: issue order ... S@t-1(4), S@t(4); vmcnt(4)@t drains
//     S@t-1 -> t+1 resident at BAR2. Prologue: S(t0)+S(t1), vmcnt(4) = t0
//     resident. Tail: vmcnt(0)@NT-2 -> NT-1 resident.
//   - LDS 64 KB: As[2][8192] + Bs[2][8192] (256 rows x 32 cols bf16 each).
//     Chunk-XOR swizzle: row r, k-chunk q (16B) stored at slot q^(r&3);
//     slot = q^(fr&3) is LANE-CONSTANT -> 1 addr VGPR/operand, all reads
//     via imm offsets. Staging source pre-swizzled (both-sides rule #21).
//     Wave b128 read touches 16 rows x full 64B = every bank 2x = free.
//   - Per-acc-element K order: one MFMA per 32-chunk, ascending t (q4@t at
//     head of t+1 is still ordered per element) -> bit-identical to R2.
//   - Epilogue j-innermost (R2-verified: WRITE_SIZE == output size).
// ---------------------------------------------------------------------------
#define GROUP_M 8
#define MFMA_B16(a, b, c) __builtin_amdgcn_mfma_f32_16x16x32_bf16(a, b, c, 0, 0, 0)
#define SBAR __builtin_amdgcn_sched_barrier(0)

template<bool QP, bool ST, int VMC, bool BARS, bool PRE>
__device__ __forceinline__ void ktile32(
    const unsigned short* AsB, const unsigned short* BsB,   // cur buf bases
    unsigned short* AsS, unsigned short* BsS,               // staging dest (cur)
    const unsigned short* AsN, const unsigned short* BsN,   // next buf bases
    const unsigned short* gA0, const unsigned short* gA1,
    const unsigned short* gB0, const unsigned short* gB1,
    int kk2, int ldstA, int ofsA, int ofsB,
    bf16x8 (&ha0)[4], bf16x8 (&hb0)[2],   // in: this tile a0,b0 (pre-issued)
    bf16x8 (&na0)[4], bf16x8 (&nb0)[2],   // out: next tile a0,b0
    bf16x8 (&ca1)[4], bf16x8 (&cb1)[2],   // in: prev tile a1,b1 (q4')
    bf16x8 (&ta1)[4], bf16x8 (&tb1)[2],   // out: this tile a1,b1
    f32x4 (&acc)[8][4])
{
  // ph1: issue b1 | q4'(t-1) | lgkm(2) | q1
#pragma unroll
  for (int j = 0; j < 2; ++j)
    tb1[j] = *(const bf16x8*)(BsB + ofsB + (j + 2) * 512);
  SBAR;
  if (QP) {
    __builtin_amdgcn_s_setprio(1);
#pragma unroll
    for (int i = 0; i < 4; ++i)
#pragma unroll
      for (int j = 0; j < 2; ++j)
        acc[i + 4][j + 2] = MFMA_B16(ca1[i], cb1[j], acc[i + 4][j + 2]);
    __builtin_amdgcn_s_setprio(0);
    SBAR;
  }
  asm volatile("s_waitcnt lgkmcnt(2)" ::: "memory");   // a0,b0 done (b1 out)
  SBAR;
  __builtin_amdgcn_s_setprio(1);
#pragma unroll
  for (int i = 0; i < 4; ++i)
#pragma unroll
    for (int j = 0; j < 2; ++j)
      acc[i][j] = MFMA_B16(ha0[i], hb0[j], acc[i][j]);
  __builtin_amdgcn_s_setprio(0);
  SBAR;

  // ph2: issue a1 | lgkm(4) | q2 | lgkm(0)
#pragma unroll
  for (int i = 0; i < 4; ++i)
    ta1[i] = *(const bf16x8*)(AsB + ofsA + (i + 4) * 512);
  SBAR;
  asm volatile("s_waitcnt lgkmcnt(4)" ::: "memory");   // b1 done (a1 out)
  SBAR;
  __builtin_amdgcn_s_setprio(1);
#pragma unroll
  for (int i = 0; i < 4; ++i)
#pragma unroll
    for (int j = 0; j < 2; ++j)
      acc[i][j + 2] = MFMA_B16(ha0[i], tb1[j], acc[i][j + 2]);
  __builtin_amdgcn_s_setprio(0);
  asm volatile("s_waitcnt lgkmcnt(0)" ::: "memory");   // all cur reads done
  SBAR;
  if (BARS) __builtin_amdgcn_s_barrier();              // BAR1

  // ph3: stage t+2 -> cur | q3 | vmcnt | BAR2
  if (ST) {
    async16(gA0 + kk2, AsS + ldstA);
    async16(gA1 + kk2, AsS + 4096 + ldstA);
    async16(gB0 + kk2, BsS + ldstA);
    async16(gB1 + kk2, BsS + 4096 + ldstA);
    SBAR;
  }
  __builtin_amdgcn_s_setprio(1);
#pragma unroll
  for (int i = 0; i < 4; ++i)
#pragma unroll
    for (int j = 0; j < 2; ++j)
      acc[i + 4][j] = MFMA_B16(ta1[i], hb0[j], acc[i + 4][j]);
  __builtin_amdgcn_s_setprio(0);
  if (VMC == 4)      asm volatile("s_waitcnt vmcnt(4)" ::: "memory");
  else if (VMC == 0) asm volatile("s_waitcnt vmcnt(0)" ::: "memory");
  if (BARS) __builtin_amdgcn_s_barrier();              // BAR2: t+1 resident

  // ph4: pre-issue next tile a0,b0 from next buf (drain under q3'/q4')
  if (PRE) {
#pragma unroll
    for (int i = 0; i < 4; ++i)
      na0[i] = *(const bf16x8*)(AsN + ofsA + i * 512);
#pragma unroll
    for (int j = 0; j < 2; ++j)
      nb0[j] = *(const bf16x8*)(BsN + ofsB + j * 512);
    SBAR;
  }
}

template<int OUT_BF16, int RELU>
__global__ __launch_bounds__(512, 2) void gemm_bt_256(
    const unsigned short* __restrict__ A,   // [M][K] bf16
    const unsigned short* __restrict__ Bt,  // [N][K] bf16
    const float* __restrict__ bias,         // [N] fp32
    void* __restrict__ C0, void* __restrict__ C1, int Msplit,
    int M, int N, int K)
{
  __shared__ unsigned short As[2][8192];   // 2 x 256x32 bf16 = 32 KB
  __shared__ unsigned short Bs[2][8192];   // 32 KB

  const int tid  = threadIdx.x;
  const int wave = tid >> 6;
  const int lane = tid & 63;

  // L2 block swizzle (m-panels of 256 rows)
  const int nbx = N >> 8;
  const int gsize = nbx * GROUP_M;
  const int grp = blockIdx.x / gsize, within = blockIdx.x % gsize;
  const int m0 = (grp * GROUP_M + (within % GROUP_M)) << 8;
  const int n0 = (within / GROUP_M) << 8;

  const int wm = (wave >> 2) << 7;   // 0 / 128
  const int wn = (wave & 3) << 6;    // 0 / 64 / 128 / 192

  // staging lane geometry: call = 512 lanes x 16B = 128 rows x 64B
  const int srow   = tid >> 2;                  // row within call (0..127)
  const int schunk = (tid & 3) ^ (srow & 3);    // pre-swizzled 16B chunk
  const unsigned short* gA0 = A  + (size_t)(m0 + srow) * K + schunk * 8;
  const unsigned short* gA1 = gA0 + (size_t)128 * K;
  const unsigned short* gB0 = Bt + (size_t)(n0 + srow) * K + schunk * 8;
  const unsigned short* gB1 = gB0 + (size_t)128 * K;
  const int ldstA = wave << 9;                  // wave LDS slice (ushorts)

  // fragment read geometry: lane (fr, q) reads row r=...+fr, k-chunk q;
  // stored slot = q ^ (r&3) = q ^ (fr&3)  (lane-constant)
  const int fr = lane & 15, q = lane >> 4;
  const int cs = (q ^ (fr & 3)) << 3;           // slot offset (ushorts)
  const int ofsA = ((wm + fr) << 5) + cs;
  const int ofsB = ((wn + fr) << 5) + cs;

  f32x4 acc[8][4] = {};
  bf16x8 a0A[4], b0A[2], a0B[4], b0B[2];   // head sets (pre-issued a0,b0)
  bf16x8 a1A[4], b1A[2], a1B[4], b1B[2];   // tail sets (q4 carry a1,b1)

  unsigned short* A0p = &As[0][0]; unsigned short* B0p = &Bs[0][0];
  unsigned short* A1p = &As[1][0]; unsigned short* B1p = &Bs[1][0];

  // prologue: stage tile0 -> buf0, tile1 -> buf1; vmcnt(4) = tile0 resident
  async16(gA0,      A0p + ldstA);
  async16(gA1,      A0p + 4096 + ldstA);
  async16(gB0,      B0p + ldstA);
  async16(gB1,      B0p + 4096 + ldstA);
  async16(gA0 + 32, A1p + ldstA);
  async16(gA1 + 32, A1p + 4096 + ldstA);
  async16(gB0 + 32, B1p + ldstA);
  async16(gB1 + 32, B1p + 4096 + ldstA);
  asm volatile("s_waitcnt vmcnt(4)" ::: "memory");
  __builtin_amdgcn_s_barrier();
  // issue a0,b0 of tile0 (6 reads, buf0)
#pragma unroll
  for (int i = 0; i < 4; ++i)
    a0A[i] = *(const bf16x8*)(A0p + ofsA + i * 512);
#pragma unroll
  for (int j = 0; j < 2; ++j)
    b0A[j] = *(const bf16x8*)(B0p + ofsB + j * 512);
  SBAR;

  const int NT = K >> 5;   // 32 (GEMM1) or 64 (GEMM2); even, >= 8

  // t = 0 (even): no q4' yet
  ktile32<false, true, 4, true, true>(A0p, B0p, A0p, B0p, A1p, B1p,
      gA0, gA1, gB0, gB1, 2 * 32, ldstA, ofsA, ofsB,
      a0A, b0A, a0B, b0B, a1B, b1B, a1A, b1A, acc);
  // t = 1 .. NT-4 in pairs (odd, even)
#pragma unroll 1
  for (int t = 1; t <= NT - 5; t += 2) {
    ktile32<true, true, 4, true, true>(A1p, B1p, A1p, B1p, A0p, B0p,
        gA0, gA1, gB0, gB1, (t + 2) * 32, ldstA, ofsA, ofsB,
        a0B, b0B, a0A, b0A, a1A, b1A, a1B, b1B, acc);
    ktile32<true, true, 4, true, true>(A0p, B0p, A0p, B0p, A1p, B1p,
        gA0, gA1, gB0, gB1, (t + 3) * 32, ldstA, ofsA, ofsB,
        a0A, b0A, a0B, b0B, a1B, b1B, a1A, b1A, acc);
  }
  // t = NT-3 (odd), full
  ktile32<true, true, 4, true, true>(A1p, B1p, A1p, B1p, A0p, B0p,
      gA0, gA1, gB0, gB1, (NT - 1) * 32, ldstA, ofsA, ofsB,
      a0B, b0B, a0A, b0A, a1A, b1A, a1B, b1B, acc);
  // t = NT-2 (even): no stage; vmcnt(0) -> tile NT-1 resident; PRE
  ktile32<true, false, 0, true, true>(A0p, B0p, A0p, B0p, A1p, B1p,
      gA0, gA1, gB0, gB1, 0, ldstA, ofsA, ofsB,
      a0A, b0A, a0B, b0B, a1B, b1B, a1A, b1A, acc);
  // t = NT-1 (odd): no stage/barriers/pre
  ktile32<true, false, -1, false, false>(A1p, B1p, A1p, B1p, A0p, B0p,
      gA0, gA1, gB0, gB1, 0, ldstA, ofsA, ofsB,
      a0B, b0B, a0A, b0A, a1A, b1A, a1B, b1B, acc);
  // final q4 of tile NT-1 (tail set B)
  __builtin_amdgcn_s_setprio(1);
#pragma unroll
  for (int i = 0; i < 4; ++i)
#pragma unroll
    for (int j = 0; j < 2; ++j)
      acc[i + 4][j + 2] = MFMA_B16(a1B[i], b1B[j], acc[i + 4][j + 2]);
  __builtin_amdgcn_s_setprio(0);

  // epilogue: bias + optional relu; per-block output select (tile-aligned)
  // C/D layout: col = lane&15, row = (lane>>4)*4 + reg   [m89/m91 verified]
  // j INNERMOST: each 128B output line completed in 4 consecutive stores
  void* Cb = (m0 < Msplit) ? C0 : C1;
  const int mbase = (m0 < Msplit) ? m0 : (m0 - Msplit);
  const int crow = mbase + wm + (lane >> 4) * 4;
  const int ccol = n0 + wn + (lane & 15);
  float bv[4];
#pragma unroll
  for (int j = 0; j < 4; ++j) bv[j] = bias[ccol + j * 16];
#pragma unroll
  for (int i = 0; i < 8; ++i) {
#pragma unroll
    for (int r = 0; r < 4; ++r) {
      size_t base = (size_t)(crow + i * 16 + r) * N + ccol;
#pragma unroll
      for (int j = 0; j < 4; ++j) {
        float v = acc[i][j][r] + bv[j];
        if (RELU) v = fmaxf(v, 0.0f);
        if (OUT_BF16) ((unsigned short*)Cb)[base + j * 16] = f2bf(v);
        else          ((float*)Cb)[base + j * 16] = v;
      }
    }
  }
}

// ---------------------------------------------------------------------------
// post_kernel: comb (blocks [0, SUNL/2)) + yhat (blocks [SUNL/2, +SLAB/4))
// ---------------------------------------------------------------------------
#define COMB_BLOCKS (SUNL / 2)              // 8192
#define YHAT_BLOCKS (SLAB / 4)              // 2048
#define POST_BLOCKS (COMB_BLOCKS + YHAT_BLOCKS)

__global__ __launch_bounds__(256) void post_kernel(
    const float* __restrict__ feat_l, const float* __restrict__ W3,
    const float* __restrict__ b3, const int* __restrict__ ia,
    const int* __restrict__ ib, const float* __restrict__ kv,
    float* __restrict__ out_comb, float* __restrict__ out_yhat)
{
  int b = blockIdx.x;
  if (b < COMB_BLOCKS) {
    int row = b * 2 + (threadIdx.x >> 7);
    int c = (threadIdx.x & 127) << 2;
    float k = kv[row];
    float km1 = 1.0f - k;
    float4 fa = *(const float4*)(feat_l + (size_t)ia[row] * HID2 + c);
    float4 fb = *(const float4*)(feat_l + (size_t)ib[row] * HID2 + c);
    float4 o;
    o.x = k * fa.x + km1 * fb.x;
    o.y = k * fa.y + km1 * fb.y;
    o.z = k * fa.z + km1 * fb.z;
    o.w = k * fa.w + km1 * fb.w;
    *(float4*)(out_comb + (size_t)row * HID2 + c) = o;
  } else {
    int wave = threadIdx.x >> 6;
    int lane = threadIdx.x & 63;
    int row = (b - COMB_BLOCKS) * 4 + wave;
    const float* f = feat_l + (size_t)row * HID2;
    float s = 0.f;
#pragma unroll
    for (int j = 0; j < HID2 / 64; ++j) s = fmaf(f[lane + j * 64], W3[lane + j * 64], s);
#pragma unroll
    for (int off = 32; off; off >>= 1) s += __shfl_down(s, off);
    if (lane == 0) out_yhat[row] = s + b3[0];
  }
}

// ---------------------------------------------------------------------------
extern "C" void kernel_launch(void* const* d_in, const int* in_sizes, int n_in,
                              void* d_out, int out_size, void* d_ws, size_t ws_size,
                              hipStream_t stream)
{
  const float* X_l = (const float*)d_in[0];
  const float* y_l = (const float*)d_in[1];
  const float* X_u = (const float*)d_in[2];
  const float* y_u = (const float*)d_in[3];
  const float* W1  = (const float*)d_in[4];
  const float* b1  = (const float*)d_in[5];
  const float* W2  = (const float*)d_in[6];
  const float* b2  = (const float*)d_in[7];
  const float* W3  = (const float*)d_in[8];
  const float* b3  = (const float*)d_in[9];

  float* out_featu = (float*)d_out;
  float* out_comb  = out_featu + (size_t)SUNL * HID2;
  float* out_yhat  = out_comb + (size_t)SUNL * HID2;

  // Workspace (~174 MB): X_bf = [Xl|Xu] contig, H_bf = [Hl|Hu] contig
  unsigned short* X_bf  = (unsigned short*)d_ws;                 // [24576][1024]
  unsigned short* W1T   = X_bf + (size_t)MTOT * DIMX;
  unsigned short* W2T   = W1T + (size_t)HID1 * DIMX;
  unsigned short* H_bf  = W2T + (size_t)HID2 * HID1;             // [24576][2048]
  float* feat_l = (float*)(H_bf + (size_t)MTOT * HID1);
  int*   ai = (int*)(feat_l + (size_t)SLAB * HID2);
  int*   bi = ai + SUNL;
  float* kv = (float*)(bi + SUNL);

  prep_kernel<<<dim3(PREP_BLOCKS), dim3(256), 0, stream>>>(
      X_l, X_u, W1, W2, y_l, y_u, X_bf, W1T, W2T, ai, bi, kv);

  // layer 1 (merged l+u): H = relu(X @ W1 + b1) -> bf16  [768 blocks x 512]
  gemm_bt_256<1, 1><<<dim3((HID1 / 256) * (MTOT / 256)), dim3(512), 0, stream>>>(
      X_bf, W1T, b1, H_bf, H_bf, MTOT /*no split*/, MTOT, HID1, DIMX);

  // layer 2 (merged l+u): feat = relu(H @ W2 + b2) -> fp32, split dest [192 blocks]
  gemm_bt_256<0, 1><<<dim3((HID2 / 256) * (MTOT / 256)), dim3(512), 0, stream>>>(
      H_bf, W2T, b2, feat_l, out_featu, SLAB, MTOT, HID2, HID1);

  post_kernel<<<dim3(POST_BLOCKS), dim3(256), 0, stream>>>(
      feat_l, W3, b3, ai, bi, kv, out_comb, out_yhat);
}

// Round 6
// 333.032 us; speedup vs baseline: 1.9311x; 1.0206x over previous
//
#include <hip/hip_runtime.h>
#include <stdint.h>

// Problem constants (match reference)
#define SLAB 8192    // SL
#define SUNL 16384   // SU
#define DIMX 1024
#define HID1 2048
#define HID2 512
#define KTRIES 8
#define MTOT (SLAB + SUNL)   // 24576

typedef __attribute__((ext_vector_type(8))) short bf16x8;    // 8 bf16 = 4 VGPRs
typedef __attribute__((ext_vector_type(4))) float f32x4;

// fp32 -> bf16 round-to-nearest-even
__device__ __forceinline__ unsigned short f2bf(float f) {
  union { float f; uint32_t u; } c; c.f = f;
  return (unsigned short)((c.u + 0x7fffu + ((c.u >> 16) & 1u)) >> 16);
}

// async global->LDS, 16B per lane; lds dest = wave-uniform base + lane*16
__device__ __forceinline__ void async16(const void* g, void* l) {
  __builtin_amdgcn_global_load_lds(
      (const __attribute__((address_space(1))) unsigned int*)g,
      (__attribute__((address_space(3))) unsigned int*)l,
      16, 0, 0);
}

// ---------------------------------------------------------------------------
// Threefry2x32 (JAX-compatible, 20 rounds)
// ---------------------------------------------------------------------------
struct U2 { uint32_t x, y; };

__device__ __forceinline__ U2 threefry(uint32_t k0, uint32_t k1, uint32_t x0, uint32_t x1) {
  uint32_t ks2 = k0 ^ k1 ^ 0x1BD11BDAu;
  x0 += k0; x1 += k1;
#define TF_R(r) { x0 += x1; x1 = (x1 << (r)) | (x1 >> (32 - (r))); x1 ^= x0; }
  TF_R(13) TF_R(15) TF_R(26) TF_R(6)
  x0 += k1; x1 += ks2 + 1u;
  TF_R(17) TF_R(29) TF_R(16) TF_R(24)
  x0 += ks2; x1 += k0 + 2u;
  TF_R(13) TF_R(15) TF_R(26) TF_R(6)
  x0 += k0; x1 += k1 + 3u;
  TF_R(17) TF_R(29) TF_R(16) TF_R(24)
  x0 += k1; x1 += ks2 + 4u;
  TF_R(13) TF_R(15) TF_R(26) TF_R(6)
  x0 += ks2; x1 += k0 + 5u;
#undef TF_R
  return {x0, x1};
}

// ---------------------------------------------------------------------------
// prep_kernel: one launch for cast(X_l|X_u), transpose-cast W1, W2, and pairs.
// ---------------------------------------------------------------------------
#define XL_BLOCKS (SLAB * DIMX / 4 / 256)           // 8192
#define CAST_BLOCKS (MTOT * DIMX / 4 / 256)         // 24576
#define T1_NBX (HID1 / 32)                          // 64
#define T1_BLOCKS ((HID1 / 32) * (DIMX / 32))       // 2048
#define T2_NBX (HID2 / 32)                          // 16
#define T2_BLOCKS ((HID2 / 32) * (HID1 / 32))       // 1024
#define PAIR_BLOCKS (SUNL / 256)                    // 64
#define PREP_BLOCKS (CAST_BLOCKS + T1_BLOCKS + T2_BLOCKS + PAIR_BLOCKS)

__global__ __launch_bounds__(256) void prep_kernel(
    const float* __restrict__ Xl, const float* __restrict__ Xu,
    const float* __restrict__ W1, const float* __restrict__ W2,
    const float* __restrict__ y_l, const float* __restrict__ y_u,
    unsigned short* __restrict__ X_bf, unsigned short* __restrict__ W1T,
    unsigned short* __restrict__ W2T,
    int* __restrict__ ia, int* __restrict__ ib, float* __restrict__ kv)
{
  __shared__ float t[32][33];
  int b = blockIdx.x;
  int tid = threadIdx.x;

  if (b < CAST_BLOCKS) {
    const float* src; size_t i, doff;
    if (b < XL_BLOCKS) { src = Xl; i = (size_t)b * 256 + tid; doff = 0; }
    else { src = Xu; i = (size_t)(b - XL_BLOCKS) * 256 + tid; doff = (size_t)SLAB * DIMX / 4; }
    float4 v = ((const float4*)src)[i];
    ushort4 o;
    o.x = f2bf(v.x); o.y = f2bf(v.y); o.z = f2bf(v.z); o.w = f2bf(v.w);
    ((ushort4*)X_bf)[doff + i] = o;
  } else if (b < CAST_BLOCKS + T1_BLOCKS + T2_BLOCKS) {
    const float* W; unsigned short* WT; int K, N, bx, by;
    if (b < CAST_BLOCKS + T1_BLOCKS) {
      int tb = b - CAST_BLOCKS;
      W = W1; WT = W1T; K = DIMX; N = HID1; bx = tb % T1_NBX; by = tb / T1_NBX;
    } else {
      int tb = b - CAST_BLOCKS - T1_BLOCKS;
      W = W2; WT = W2T; K = HID1; N = HID2; bx = tb % T2_NBX; by = tb / T2_NBX;
    }
    int k0 = by * 32, n0 = bx * 32;
    int tx = tid & 31, ty = tid >> 5;
#pragma unroll
    for (int i = 0; i < 32; i += 8)
      t[ty + i][tx] = W[(size_t)(k0 + ty + i) * N + n0 + tx];
    __syncthreads();
#pragma unroll
    for (int i = 0; i < 32; i += 8)
      WT[(size_t)(n0 + ty + i) * K + k0 + tx] = f2bf(t[tx][ty + i]);
  } else {
    // pair sampling (verified R1: partitionable threefry, bits1^bits2, &8191)
    int r = (b - CAST_BLOCKS - T1_BLOCKS - T2_BLOCKS) * 256 + tid;
    U2 ka  = threefry(0u, 42u, 0u, 0u);
    U2 kb  = threefry(0u, 42u, 0u, 1u);
    U2 k2a = threefry(ka.x, ka.y, 0u, 1u);
    U2 k2b = threefry(kb.x, kb.y, 0u, 1u);
    int iav[KTRIES], ibv[KTRIES];
#pragma unroll
    for (int c = 0; c < KTRIES; ++c) {
      uint32_t tt = (uint32_t)(r * KTRIES + c);
      U2 oa = threefry(k2a.x, k2a.y, 0u, tt);
      U2 ob = threefry(k2b.x, k2b.y, 0u, tt);
      iav[c] = (int)((oa.x ^ oa.y) & (SLAB - 1));
      ibv[c] = (int)((ob.x ^ ob.y) & (SLAB - 1));
    }
    int a = iav[0], bb2 = ibv[0];
#pragma unroll
    for (int c = 0; c < KTRIES; ++c) {
      if (iav[c] != ibv[c] && y_l[iav[c]] != y_l[ibv[c]]) { a = iav[c]; bb2 = ibv[c]; break; }
    }
    float ya = y_l[a], yb = y_l[bb2];
    ia[r] = a; ib[r] = bb2; kv[r] = (y_u[r] - yb) / (ya - yb);
  }
}

// ---------------------------------------------------------------------------
// bf16 MFMA GEMM, 256x256 tile, BK=32, one-quadrant rotation + pre-issued
// head reads (R6 = R5 + bank-conflict fix):
//   - R5 measured EXACTLY 4.0 conflict-cycles per ds_read_b128 (9,437,184 /
//     2,359,296 reads). Cause: 64B rows alias banks with period 2 rows
//     (64B = 16 banks), and the R5 XOR key (r&3) left rows {0,4,8,12}
//     (same parity, same key) on identical banks -> 4-way.
//   - FIX: XOR key = (r>>1)&3. slot = q ^ ((r>>1)&3): within each bank
//     half (row parity), the 8 rows map 2-per-slot -> 2-way = free on
//     wave64 (m136). ~384 conflict-cyc/tile removed (~13% of tile time).
//     Applied BOTH sides (rule #21): read cs AND pre-swizzled global
//     source schunk. Lane-constancy: row offsets (wm,wn,i*16,j*16) are
//     multiples of 32 rows in >>1 space mod 4 -> key = (fr>>1)&3.
//   - Everything else identical to R5 (passed, no spill, VGPR 116):
//     * 512 thr = 8 waves (2Mx4N), wave tile 128x64 = 8x4 MFMA 16x16x32
//     * 256-reg wall: frag pool 96 VGPR + addr + acc 128 AGPR ~ 244
//     * per tile: ph1 issue b1 | q4'(t-1) | lgkm(2) | q1 ; ph2 issue a1 |
//       lgkm(4) | q2 | lgkm(0) BAR1 ; ph3 stage t+2 | q3 | vmcnt(4) BAR2 ;
//       ph4 pre-issue {a0,b0}@t+1 (drain under next q4'/q1)
//     * vmcnt ledger: S@t-1(4)+S@t(4) outstanding; vmcnt(4) -> t+1 resident
//     * LDS 64 KB: As/Bs[2][8192] (256 rows x 32 cols bf16)
//     * per-acc-element K order ascending -> bit-identical output
//     * epilogue j-innermost (WRITE_SIZE == output, R2-verified)
// ---------------------------------------------------------------------------
#define GROUP_M 8
#define MFMA_B16(a, b, c) __builtin_amdgcn_mfma_f32_16x16x32_bf16(a, b, c, 0, 0, 0)
#define SBAR __builtin_amdgcn_sched_barrier(0)

template<bool QP, bool ST, int VMC, bool BARS, bool PRE>
__device__ __forceinline__ void ktile32(
    const unsigned short* AsB, const unsigned short* BsB,   // cur buf bases
    unsigned short* AsS, unsigned short* BsS,               // staging dest (cur)
    const unsigned short* AsN, const unsigned short* BsN,   // next buf bases
    const unsigned short* gA0, const unsigned short* gA1,
    const unsigned short* gB0, const unsigned short* gB1,
    int kk2, int ldstA, int ofsA, int ofsB,
    bf16x8 (&ha0)[4], bf16x8 (&hb0)[2],   // in: this tile a0,b0 (pre-issued)
    bf16x8 (&na0)[4], bf16x8 (&nb0)[2],   // out: next tile a0,b0
    bf16x8 (&ca1)[4], bf16x8 (&cb1)[2],   // in: prev tile a1,b1 (q4')
    bf16x8 (&ta1)[4], bf16x8 (&tb1)[2],   // out: this tile a1,b1
    f32x4 (&acc)[8][4])
{
  // ph1: issue b1 | q4'(t-1) | lgkm(2) | q1
#pragma unroll
  for (int j = 0; j < 2; ++j)
    tb1[j] = *(const bf16x8*)(BsB + ofsB + (j + 2) * 512);
  SBAR;
  if (QP) {
    __builtin_amdgcn_s_setprio(1);
#pragma unroll
    for (int i = 0; i < 4; ++i)
#pragma unroll
      for (int j = 0; j < 2; ++j)
        acc[i + 4][j + 2] = MFMA_B16(ca1[i], cb1[j], acc[i + 4][j + 2]);
    __builtin_amdgcn_s_setprio(0);
    SBAR;
  }
  asm volatile("s_waitcnt lgkmcnt(2)" ::: "memory");   // a0,b0 done (b1 out)
  SBAR;
  __builtin_amdgcn_s_setprio(1);
#pragma unroll
  for (int i = 0; i < 4; ++i)
#pragma unroll
    for (int j = 0; j < 2; ++j)
      acc[i][j] = MFMA_B16(ha0[i], hb0[j], acc[i][j]);
  __builtin_amdgcn_s_setprio(0);
  SBAR;

  // ph2: issue a1 | lgkm(4) | q2 | lgkm(0)
#pragma unroll
  for (int i = 0; i < 4; ++i)
    ta1[i] = *(const bf16x8*)(AsB + ofsA + (i + 4) * 512);
  SBAR;
  asm volatile("s_waitcnt lgkmcnt(4)" ::: "memory");   // b1 done (a1 out)
  SBAR;
  __builtin_amdgcn_s_setprio(1);
#pragma unroll
  for (int i = 0; i < 4; ++i)
#pragma unroll
    for (int j = 0; j < 2; ++j)
      acc[i][j + 2] = MFMA_B16(ha0[i], tb1[j], acc[i][j + 2]);
  __builtin_amdgcn_s_setprio(0);
  asm volatile("s_waitcnt lgkmcnt(0)" ::: "memory");   // all cur reads done
  SBAR;
  if (BARS) __builtin_amdgcn_s_barrier();              // BAR1

  // ph3: stage t+2 -> cur | q3 | vmcnt | BAR2
  if (ST) {
    async16(gA0 + kk2, AsS + ldstA);
    async16(gA1 + kk2, AsS + 4096 + ldstA);
    async16(gB0 + kk2, BsS + ldstA);
    async16(gB1 + kk2, BsS + 4096 + ldstA);
    SBAR;
  }
  __builtin_amdgcn_s_setprio(1);
#pragma unroll
  for (int i = 0; i < 4; ++i)
#pragma unroll
    for (int j = 0; j < 2; ++j)
      acc[i + 4][j] = MFMA_B16(ta1[i], hb0[j], acc[i + 4][j]);
  __builtin_amdgcn_s_setprio(0);
  if (VMC == 4)      asm volatile("s_waitcnt vmcnt(4)" ::: "memory");
  else if (VMC == 0) asm volatile("s_waitcnt vmcnt(0)" ::: "memory");
  if (BARS) __builtin_amdgcn_s_barrier();              // BAR2: t+1 resident

  // ph4: pre-issue next tile a0,b0 from next buf (drain under q3'/q4')
  if (PRE) {
#pragma unroll
    for (int i = 0; i < 4; ++i)
      na0[i] = *(const bf16x8*)(AsN + ofsA + i * 512);
#pragma unroll
    for (int j = 0; j < 2; ++j)
      nb0[j] = *(const bf16x8*)(BsN + ofsB + j * 512);
    SBAR;
  }
}

template<int OUT_BF16, int RELU>
__global__ __launch_bounds__(512, 2) void gemm_bt_256(
    const unsigned short* __restrict__ A,   // [M][K] bf16
    const unsigned short* __restrict__ Bt,  // [N][K] bf16
    const float* __restrict__ bias,         // [N] fp32
    void* __restrict__ C0, void* __restrict__ C1, int Msplit,
    int M, int N, int K)
{
  __shared__ unsigned short As[2][8192];   // 2 x 256x32 bf16 = 32 KB
  __shared__ unsigned short Bs[2][8192];   // 32 KB

  const int tid  = threadIdx.x;
  const int wave = tid >> 6;
  const int lane = tid & 63;

  // L2 block swizzle (m-panels of 256 rows)
  const int nbx = N >> 8;
  const int gsize = nbx * GROUP_M;
  const int grp = blockIdx.x / gsize, within = blockIdx.x % gsize;
  const int m0 = (grp * GROUP_M + (within % GROUP_M)) << 8;
  const int n0 = (within / GROUP_M) << 8;

  const int wm = (wave >> 2) << 7;   // 0 / 128
  const int wn = (wave & 3) << 6;    // 0 / 64 / 128 / 192

  // staging lane geometry: call = 512 lanes x 16B = 128 rows x 64B
  // pre-swizzled chunk key = (row>>1)&3  (row aliasing period is 2 rows
  // at 64B stride; R5's (row&3) key left a 4-way conflict)
  const int srow   = tid >> 2;                       // row within call (0..127)
  const int schunk = (tid & 3) ^ ((srow >> 1) & 3);  // pre-swizzled 16B chunk
  const unsigned short* gA0 = A  + (size_t)(m0 + srow) * K + schunk * 8;
  const unsigned short* gA1 = gA0 + (size_t)128 * K;
  const unsigned short* gB0 = Bt + (size_t)(n0 + srow) * K + schunk * 8;
  const unsigned short* gB1 = gB0 + (size_t)128 * K;
  const int ldstA = wave << 9;                  // wave LDS slice (ushorts)

  // fragment read geometry: lane (fr, q) reads row r=...+fr, k-chunk q;
  // stored slot = q ^ ((r>>1)&3) = q ^ ((fr>>1)&3)  (lane-constant)
  const int fr = lane & 15, q = lane >> 4;
  const int cs = (q ^ ((fr >> 1) & 3)) << 3;    // slot offset (ushorts)
  const int ofsA = ((wm + fr) << 5) + cs;
  const int ofsB = ((wn + fr) << 5) + cs;

  f32x4 acc[8][4] = {};
  bf16x8 a0A[4], b0A[2], a0B[4], b0B[2];   // head sets (pre-issued a0,b0)
  bf16x8 a1A[4], b1A[2], a1B[4], b1B[2];   // tail sets (q4 carry a1,b1)

  unsigned short* A0p = &As[0][0]; unsigned short* B0p = &Bs[0][0];
  unsigned short* A1p = &As[1][0]; unsigned short* B1p = &Bs[1][0];

  // prologue: stage tile0 -> buf0, tile1 -> buf1; vmcnt(4) = tile0 resident
  async16(gA0,      A0p + ldstA);
  async16(gA1,      A0p + 4096 + ldstA);
  async16(gB0,      B0p + ldstA);
  async16(gB1,      B0p + 4096 + ldstA);
  async16(gA0 + 32, A1p + ldstA);
  async16(gA1 + 32, A1p + 4096 + ldstA);
  async16(gB0 + 32, B1p + ldstA);
  async16(gB1 + 32, B1p + 4096 + ldstA);
  asm volatile("s_waitcnt vmcnt(4)" ::: "memory");
  __builtin_amdgcn_s_barrier();
  // issue a0,b0 of tile0 (6 reads, buf0)
#pragma unroll
  for (int i = 0; i < 4; ++i)
    a0A[i] = *(const bf16x8*)(A0p + ofsA + i * 512);
#pragma unroll
  for (int j = 0; j < 2; ++j)
    b0A[j] = *(const bf16x8*)(B0p + ofsB + j * 512);
  SBAR;

  const int NT = K >> 5;   // 32 (GEMM1) or 64 (GEMM2); even, >= 8

  // t = 0 (even): no q4' yet
  ktile32<false, true, 4, true, true>(A0p, B0p, A0p, B0p, A1p, B1p,
      gA0, gA1, gB0, gB1, 2 * 32, ldstA, ofsA, ofsB,
      a0A, b0A, a0B, b0B, a1B, b1B, a1A, b1A, acc);
  // t = 1 .. NT-4 in pairs (odd, even)
#pragma unroll 1
  for (int t = 1; t <= NT - 5; t += 2) {
    ktile32<true, true, 4, true, true>(A1p, B1p, A1p, B1p, A0p, B0p,
        gA0, gA1, gB0, gB1, (t + 2) * 32, ldstA, ofsA, ofsB,
        a0B, b0B, a0A, b0A, a1A, b1A, a1B, b1B, acc);
    ktile32<true, true, 4, true, true>(A0p, B0p, A0p, B0p, A1p, B1p,
        gA0, gA1, gB0, gB1, (t + 3) * 32, ldstA, ofsA, ofsB,
        a0A, b0A, a0B, b0B, a1B, b1B, a1A, b1A, acc);
  }
  // t = NT-3 (odd), full
  ktile32<true, true, 4, true, true>(A1p, B1p, A1p, B1p, A0p, B0p,
      gA0, gA1, gB0, gB1, (NT - 1) * 32, ldstA, ofsA, ofsB,
      a0B, b0B, a0A, b0A, a1A, b1A, a1B, b1B, acc);
  // t = NT-2 (even): no stage; vmcnt(0) -> tile NT-1 resident; PRE
  ktile32<true, false, 0, true, true>(A0p, B0p, A0p, B0p, A1p, B1p,
      gA0, gA1, gB0, gB1, 0, ldstA, ofsA, ofsB,
      a0A, b0A, a0B, b0B, a1B, b1B, a1A, b1A, acc);
  // t = NT-1 (odd): no stage/barriers/pre
  ktile32<true, false, -1, false, false>(A1p, B1p, A1p, B1p, A0p, B0p,
      gA0, gA1, gB0, gB1, 0, ldstA, ofsA, ofsB,
      a0B, b0B, a0A, b0A, a1A, b1A, a1B, b1B, acc);
  // final q4 of tile NT-1 (tail set B)
  __builtin_amdgcn_s_setprio(1);
#pragma unroll
  for (int i = 0; i < 4; ++i)
#pragma unroll
    for (int j = 0; j < 2; ++j)
      acc[i + 4][j + 2] = MFMA_B16(a1B[i], b1B[j], acc[i + 4][j + 2]);
  __builtin_amdgcn_s_setprio(0);

  // epilogue: bias + optional relu; per-block output select (tile-aligned)
  // C/D layout: col = lane&15, row = (lane>>4)*4 + reg   [m89/m91 verified]
  // j INNERMOST: each 128B output line completed in 4 consecutive stores
  void* Cb = (m0 < Msplit) ? C0 : C1;
  const int mbase = (m0 < Msplit) ? m0 : (m0 - Msplit);
  const int crow = mbase + wm + (lane >> 4) * 4;
  const int ccol = n0 + wn + (lane & 15);
  float bv[4];
#pragma unroll
  for (int j = 0; j < 4; ++j) bv[j] = bias[ccol + j * 16];
#pragma unroll
  for (int i = 0; i < 8; ++i) {
#pragma unroll
    for (int r = 0; r < 4; ++r) {
      size_t base = (size_t)(crow + i * 16 + r) * N + ccol;
#pragma unroll
      for (int j = 0; j < 4; ++j) {
        float v = acc[i][j][r] + bv[j];
        if (RELU) v = fmaxf(v, 0.0f);
        if (OUT_BF16) ((unsigned short*)Cb)[base + j * 16] = f2bf(v);
        else          ((float*)Cb)[base + j * 16] = v;
      }
    }
  }
}

// ---------------------------------------------------------------------------
// post_kernel: comb (blocks [0, SUNL/2)) + yhat (blocks [SUNL/2, +SLAB/4))
// ---------------------------------------------------------------------------
#define COMB_BLOCKS (SUNL / 2)              // 8192
#define YHAT_BLOCKS (SLAB / 4)              // 2048
#define POST_BLOCKS (COMB_BLOCKS + YHAT_BLOCKS)

__global__ __launch_bounds__(256) void post_kernel(
    const float* __restrict__ feat_l, const float* __restrict__ W3,
    const float* __restrict__ b3, const int* __restrict__ ia,
    const int* __restrict__ ib, const float* __restrict__ kv,
    float* __restrict__ out_comb, float* __restrict__ out_yhat)
{
  int b = blockIdx.x;
  if (b < COMB_BLOCKS) {
    int row = b * 2 + (threadIdx.x >> 7);
    int c = (threadIdx.x & 127) << 2;
    float k = kv[row];
    float km1 = 1.0f - k;
    float4 fa = *(const float4*)(feat_l + (size_t)ia[row] * HID2 + c);
    float4 fb = *(const float4*)(feat_l + (size_t)ib[row] * HID2 + c);
    float4 o;
    o.x = k * fa.x + km1 * fb.x;
    o.y = k * fa.y + km1 * fb.y;
    o.z = k * fa.z + km1 * fb.z;
    o.w = k * fa.w + km1 * fb.w;
    *(float4*)(out_comb + (size_t)row * HID2 + c) = o;
  } else {
    int wave = threadIdx.x >> 6;
    int lane = threadIdx.x & 63;
    int row = (b - COMB_BLOCKS) * 4 + wave;
    const float* f = feat_l + (size_t)row * HID2;
    float s = 0.f;
#pragma unroll
    for (int j = 0; j < HID2 / 64; ++j) s = fmaf(f[lane + j * 64], W3[lane + j * 64], s);
#pragma unroll
    for (int off = 32; off; off >>= 1) s += __shfl_down(s, off);
    if (lane == 0) out_yhat[row] = s + b3[0];
  }
}

// ---------------------------------------------------------------------------
extern "C" void kernel_launch(void* const* d_in, const int* in_sizes, int n_in,
                              void* d_out, int out_size, void* d_ws, size_t ws_size,
                              hipStream_t stream)
{
  const float* X_l = (const float*)d_in[0];
  const float* y_l = (const float*)d_in[1];
  const float* X_u = (const float*)d_in[2];
  const float* y_u = (const float*)d_in[3];
  const float* W1  = (const float*)d_in[4];
  const float* b1  = (const float*)d_in[5];
  const float* W2  = (const float*)d_in[6];
  const float* b2  = (const float*)d_in[7];
  const float* W3  = (const float*)d_in[8];
  const float* b3  = (const float*)d_in[9];

  float* out_featu = (float*)d_out;
  float* out_comb  = out_featu + (size_t)SUNL * HID2;
  float* out_yhat  = out_comb + (size_t)SUNL * HID2;

  // Workspace (~174 MB): X_bf = [Xl|Xu] contig, H_bf = [Hl|Hu] contig
  unsigned short* X_bf  = (unsigned short*)d_ws;                 // [24576][1024]
  unsigned short* W1T   = X_bf + (size_t)MTOT * DIMX;
  unsigned short* W2T   = W1T + (size_t)HID1 * DIMX;
  unsigned short* H_bf  = W2T + (size_t)HID2 * HID1;             // [24576][2048]
  float* feat_l = (float*)(H_bf + (size_t)MTOT * HID1);
  int*   ai = (int*)(feat_l + (size_t)SLAB * HID2);
  int*   bi = ai + SUNL;
  float* kv = (float*)(bi + SUNL);

  prep_kernel<<<dim3(PREP_BLOCKS), dim3(256), 0, stream>>>(
      X_l, X_u, W1, W2, y_l, y_u, X_bf, W1T, W2T, ai, bi, kv);

  // layer 1 (merged l+u): H = relu(X @ W1 + b1) -> bf16  [768 blocks x 512]
  gemm_bt_256<1, 1><<<dim3((HID1 / 256) * (MTOT / 256)), dim3(512), 0, stream>>>(
      X_bf, W1T, b1, H_bf, H_bf, MTOT /*no split*/, MTOT, HID1, DIMX);

  // layer 2 (merged l+u): feat = relu(H @ W2 + b2) -> fp32, split dest [192 blocks]
  gemm_bt_256<0, 1><<<dim3((HID2 / 256) * (MTOT / 256)), dim3(512), 0, stream>>>(
      H_bf, W2T, b2, feat_l, out_featu, SLAB, MTOT, HID2, HID1);

  post_kernel<<<dim3(POST_BLOCKS), dim3(256), 0, stream>>>(
      feat_l, W3, b3, ai, bi, kv, out_comb, out_yhat);
}

// Round 7
// 329.692 us; speedup vs baseline: 1.9506x; 1.0101x over previous
//
#include <hip/hip_runtime.h>
#include <stdint.h>

// Problem constants (match reference)
#define SLAB 8192    // SL
#define SUNL 16384   // SU
#define DIMX 1024
#define HID1 2048
#define HID2 512
#define KTRIES 8
#define MTOT (SLAB + SUNL)   // 24576

typedef __attribute__((ext_vector_type(8))) short bf16x8;    // 8 bf16 = 4 VGPRs
typedef __attribute__((ext_vector_type(4))) float f32x4;

// fp32 -> bf16 round-to-nearest-even
__device__ __forceinline__ unsigned short f2bf(float f) {
  union { float f; uint32_t u; } c; c.f = f;
  return (unsigned short)((c.u + 0x7fffu + ((c.u >> 16) & 1u)) >> 16);
}

// async global->LDS, 16B per lane; lds dest = wave-uniform base + lane*16
__device__ __forceinline__ void async16(const void* g, void* l) {
  __builtin_amdgcn_global_load_lds(
      (const __attribute__((address_space(1))) unsigned int*)g,
      (__attribute__((address_space(3))) unsigned int*)l,
      16, 0, 0);
}

// ---------------------------------------------------------------------------
// Threefry2x32 (JAX-compatible, 20 rounds)
// ---------------------------------------------------------------------------
struct U2 { uint32_t x, y; };

__device__ __forceinline__ U2 threefry(uint32_t k0, uint32_t k1, uint32_t x0, uint32_t x1) {
  uint32_t ks2 = k0 ^ k1 ^ 0x1BD11BDAu;
  x0 += k0; x1 += k1;
#define TF_R(r) { x0 += x1; x1 = (x1 << (r)) | (x1 >> (32 - (r))); x1 ^= x0; }
  TF_R(13) TF_R(15) TF_R(26) TF_R(6)
  x0 += k1; x1 += ks2 + 1u;
  TF_R(17) TF_R(29) TF_R(16) TF_R(24)
  x0 += ks2; x1 += k0 + 2u;
  TF_R(13) TF_R(15) TF_R(26) TF_R(6)
  x0 += k0; x1 += k1 + 3u;
  TF_R(17) TF_R(29) TF_R(16) TF_R(24)
  x0 += k1; x1 += ks2 + 4u;
  TF_R(13) TF_R(15) TF_R(26) TF_R(6)
  x0 += ks2; x1 += k0 + 5u;
#undef TF_R
  return {x0, x1};
}

// ---------------------------------------------------------------------------
// prep_kernel: one launch for cast(X_l|X_u), transpose-cast W1, W2, and pairs.
// ---------------------------------------------------------------------------
#define XL_BLOCKS (SLAB * DIMX / 4 / 256)           // 8192
#define CAST_BLOCKS (MTOT * DIMX / 4 / 256)         // 24576
#define T1_NBX (HID1 / 32)                          // 64
#define T1_BLOCKS ((HID1 / 32) * (DIMX / 32))       // 2048
#define T2_NBX (HID2 / 32)                          // 16
#define T2_BLOCKS ((HID2 / 32) * (HID1 / 32))       // 1024
#define PAIR_BLOCKS (SUNL / 256)                    // 64
#define PREP_BLOCKS (CAST_BLOCKS + T1_BLOCKS + T2_BLOCKS + PAIR_BLOCKS)

__global__ __launch_bounds__(256) void prep_kernel(
    const float* __restrict__ Xl, const float* __restrict__ Xu,
    const float* __restrict__ W1, const float* __restrict__ W2,
    const float* __restrict__ y_l, const float* __restrict__ y_u,
    unsigned short* __restrict__ X_bf, unsigned short* __restrict__ W1T,
    unsigned short* __restrict__ W2T,
    int* __restrict__ ia, int* __restrict__ ib, float* __restrict__ kv)
{
  __shared__ float t[32][33];
  int b = blockIdx.x;
  int tid = threadIdx.x;

  if (b < CAST_BLOCKS) {
    const float* src; size_t i, doff;
    if (b < XL_BLOCKS) { src = Xl; i = (size_t)b * 256 + tid; doff = 0; }
    else { src = Xu; i = (size_t)(b - XL_BLOCKS) * 256 + tid; doff = (size_t)SLAB * DIMX / 4; }
    float4 v = ((const float4*)src)[i];
    ushort4 o;
    o.x = f2bf(v.x); o.y = f2bf(v.y); o.z = f2bf(v.z); o.w = f2bf(v.w);
    ((ushort4*)X_bf)[doff + i] = o;
  } else if (b < CAST_BLOCKS + T1_BLOCKS + T2_BLOCKS) {
    const float* W; unsigned short* WT; int K, N, bx, by;
    if (b < CAST_BLOCKS + T1_BLOCKS) {
      int tb = b - CAST_BLOCKS;
      W = W1; WT = W1T; K = DIMX; N = HID1; bx = tb % T1_NBX; by = tb / T1_NBX;
    } else {
      int tb = b - CAST_BLOCKS - T1_BLOCKS;
      W = W2; WT = W2T; K = HID1; N = HID2; bx = tb % T2_NBX; by = tb / T2_NBX;
    }
    int k0 = by * 32, n0 = bx * 32;
    int tx = tid & 31, ty = tid >> 5;
#pragma unroll
    for (int i = 0; i < 32; i += 8)
      t[ty + i][tx] = W[(size_t)(k0 + ty + i) * N + n0 + tx];
    __syncthreads();
#pragma unroll
    for (int i = 0; i < 32; i += 8)
      WT[(size_t)(n0 + ty + i) * K + k0 + tx] = f2bf(t[tx][ty + i]);
  } else {
    // pair sampling (verified R1: partitionable threefry, bits1^bits2, &8191)
    int r = (b - CAST_BLOCKS - T1_BLOCKS - T2_BLOCKS) * 256 + tid;
    U2 ka  = threefry(0u, 42u, 0u, 0u);
    U2 kb  = threefry(0u, 42u, 0u, 1u);
    U2 k2a = threefry(ka.x, ka.y, 0u, 1u);
    U2 k2b = threefry(kb.x, kb.y, 0u, 1u);
    int iav[KTRIES], ibv[KTRIES];
#pragma unroll
    for (int c = 0; c < KTRIES; ++c) {
      uint32_t tt = (uint32_t)(r * KTRIES + c);
      U2 oa = threefry(k2a.x, k2a.y, 0u, tt);
      U2 ob = threefry(k2b.x, k2b.y, 0u, tt);
      iav[c] = (int)((oa.x ^ oa.y) & (SLAB - 1));
      ibv[c] = (int)((ob.x ^ ob.y) & (SLAB - 1));
    }
    int a = iav[0], bb2 = ibv[0];
#pragma unroll
    for (int c = 0; c < KTRIES; ++c) {
      if (iav[c] != ibv[c] && y_l[iav[c]] != y_l[ibv[c]]) { a = iav[c]; bb2 = ibv[c]; break; }
    }
    float ya = y_l[a], yb = y_l[bb2];
    ia[r] = a; ib[r] = bb2; kv[r] = (y_u[r] - yb) / (ya - yb);
  }
}

// ---------------------------------------------------------------------------
// bf16 MFMA GEMM, 256x256 tile, BK=64 with TWO BK=32 sub-steps (R7):
//   - R6 diagnosis: neither MFMA (40%) nor LDS (38%) pipe saturated at
//     1 block/CU; ~1800 cyc of per-K-step overhead (lgkm chains, 2 bar,
//     vmcnt, issue) paid once per 32-K is the cost driver. R7 amortizes:
//     barriers/staging/vmcnt at 64-K granularity; the register pipeline
//     (R5/R6-verified rotation: pre-issued {a0,b0}, carry q4, counted
//     in-order lgkm 2/4/0) runs per 32-K sub-step unchanged.
//   - Per tile-64 (buf P = t&1), sub0 (k-half 0, NO barriers):
//       ph1 issue b1 | q4'(prev sub) | lgkm(2) | q1
//       ph2 issue a1 | lgkm(4) | q2 | lgkm(0)
//       ph3 q3
//       ph4 pre-issue {a0,b0} of sub1 (same buf, ofs^32)
//     sub1 (k-half 1): same +
//       BAR1 after lgkm(0)  -> all cur-buf reads DS-complete
//       stage 8 calls (full tile t+2 -> cur buf) before q3
//       vmcnt(8) [drains S@t-1 -> tile t+1 resident] + BAR2 after q3
//       ph4 pre-issue {a0,b0} of next tile sub0 (other buf, resident)
//   - vmcnt ledger: per tile 8 staging calls; at tile t's vmcnt(8):
//     queue = S@t-1(8) + S@t(8) -> drains S@t-1 exactly. Prologue stages
//     tile0+tile1 (16), vmcnt(8) = tile0 resident. Tail: tile NT-2
//     vmcnt(0) -> NT-1 resident; tile NT-1 runs barrier-free.
//   - LDS 128 KB: As/Bs[2][16384] = 256 rows x 64 cols bf16 (128B rows).
//     Swizzle = R2-VERIFIED (0 conflicts measured): element (R, c16) at
//     slot c16 ^ (R&7); read cs0 = (q ^ (fr&7))<<3, sub1 = cs0 ^ 32
//     (chunk+4 == XOR 4 since q<4); staging source pre-swizzled
//     schunk = (tid&7)^(srow&7) (both sides, rule #21).
//   - Registers: identical liveness to R6 (two rotating 12-frag sets,
//     96 VGPR + acc 128 AGPR) -> no spill (R3/R4 lesson).
//   - Per-acc-element K order ascending -> bit-identical output.
//   - Epilogue j-innermost (R2-verified: WRITE_SIZE == output size).
// ---------------------------------------------------------------------------
#define GROUP_M 8
#define MFMA_B16(a, b, c) __builtin_amdgcn_mfma_f32_16x16x32_bf16(a, b, c, 0, 0, 0)
#define SBAR __builtin_amdgcn_sched_barrier(0)

template<bool QP, bool BARS, bool ST, int VMC, bool PRE>
__device__ __forceinline__ void ksub(
    const unsigned short* AsB, const unsigned short* BsB,   // read buf
    unsigned short* AsS, unsigned short* BsS,               // staging dest
    const unsigned short* AsP, const unsigned short* BsP,   // pre-issue buf
    const unsigned short* gA, const unsigned short* gB,
    int kk2, int K, int ldst,
    int ofsA, int ofsB, int ofsAp, int ofsBp,
    bf16x8 (&ha0)[4], bf16x8 (&hb0)[2],   // in: this sub a0,b0 (pre-issued)
    bf16x8 (&na0)[4], bf16x8 (&nb0)[2],   // out: next sub a0,b0
    bf16x8 (&ca1)[4], bf16x8 (&cb1)[2],   // in: prev sub a1,b1 (q4')
    bf16x8 (&ta1)[4], bf16x8 (&tb1)[2],   // out: this sub a1,b1
    f32x4 (&acc)[8][4])
{
  // ph1: issue b1 | q4'(prev) | lgkm(2) | q1
#pragma unroll
  for (int j = 0; j < 2; ++j)
    tb1[j] = *(const bf16x8*)(BsB + ofsB + (j + 2) * 1024);
  SBAR;
  if (QP) {
    __builtin_amdgcn_s_setprio(1);
#pragma unroll
    for (int i = 0; i < 4; ++i)
#pragma unroll
      for (int j = 0; j < 2; ++j)
        acc[i + 4][j + 2] = MFMA_B16(ca1[i], cb1[j], acc[i + 4][j + 2]);
    __builtin_amdgcn_s_setprio(0);
    SBAR;
  }
  asm volatile("s_waitcnt lgkmcnt(2)" ::: "memory");   // a0,b0 done (b1 out)
  SBAR;
  __builtin_amdgcn_s_setprio(1);
#pragma unroll
  for (int i = 0; i < 4; ++i)
#pragma unroll
    for (int j = 0; j < 2; ++j)
      acc[i][j] = MFMA_B16(ha0[i], hb0[j], acc[i][j]);
  __builtin_amdgcn_s_setprio(0);
  SBAR;

  // ph2: issue a1 | lgkm(4) | q2 | lgkm(0)
#pragma unroll
  for (int i = 0; i < 4; ++i)
    ta1[i] = *(const bf16x8*)(AsB + ofsA + (i + 4) * 1024);
  SBAR;
  asm volatile("s_waitcnt lgkmcnt(4)" ::: "memory");   // b1 done (a1 out)
  SBAR;
  __builtin_amdgcn_s_setprio(1);
#pragma unroll
  for (int i = 0; i < 4; ++i)
#pragma unroll
    for (int j = 0; j < 2; ++j)
      acc[i][j + 2] = MFMA_B16(ha0[i], tb1[j], acc[i][j + 2]);
  __builtin_amdgcn_s_setprio(0);
  asm volatile("s_waitcnt lgkmcnt(0)" ::: "memory");   // all cur reads done
  SBAR;
  if (BARS) __builtin_amdgcn_s_barrier();              // BAR1
  if (ST) {
#pragma unroll
    for (int c = 0; c < 4; ++c) {
      async16(gA + (size_t)(c * 64) * K + kk2, AsS + c * 4096 + ldst);
      async16(gB + (size_t)(c * 64) * K + kk2, BsS + c * 4096 + ldst);
    }
    SBAR;
  }
  // q3 (pure register; overlaps staging issue/DMA)
  __builtin_amdgcn_s_setprio(1);
#pragma unroll
  for (int i = 0; i < 4; ++i)
#pragma unroll
    for (int j = 0; j < 2; ++j)
      acc[i + 4][j] = MFMA_B16(ta1[i], hb0[j], acc[i + 4][j]);
  __builtin_amdgcn_s_setprio(0);
  if (VMC == 8)      asm volatile("s_waitcnt vmcnt(8)" ::: "memory");
  else if (VMC == 0) asm volatile("s_waitcnt vmcnt(0)" ::: "memory");
  if (BARS) __builtin_amdgcn_s_barrier();              // BAR2: t+1 resident

  // ph4: pre-issue next sub's a0,b0 (drain under next q4'/q1)
  if (PRE) {
#pragma unroll
    for (int i = 0; i < 4; ++i)
      na0[i] = *(const bf16x8*)(AsP + ofsAp + i * 1024);
#pragma unroll
    for (int j = 0; j < 2; ++j)
      nb0[j] = *(const bf16x8*)(BsP + ofsBp + j * 1024);
    SBAR;
  }
}

template<int OUT_BF16, int RELU>
__global__ __launch_bounds__(512, 2) void gemm_bt_256(
    const unsigned short* __restrict__ A,   // [M][K] bf16
    const unsigned short* __restrict__ Bt,  // [N][K] bf16
    const float* __restrict__ bias,         // [N] fp32
    void* __restrict__ C0, void* __restrict__ C1, int Msplit,
    int M, int N, int K)
{
  __shared__ unsigned short As[2][16384];   // 2 x 256x64 bf16 = 64 KB
  __shared__ unsigned short Bs[2][16384];   // 64 KB

  const int tid  = threadIdx.x;
  const int wave = tid >> 6;
  const int lane = tid & 63;

  // L2 block swizzle (m-panels of 256 rows)
  const int nbx = N >> 8;
  const int gsize = nbx * GROUP_M;
  const int grp = blockIdx.x / gsize, within = blockIdx.x % gsize;
  const int m0 = (grp * GROUP_M + (within % GROUP_M)) << 8;
  const int n0 = (within / GROUP_M) << 8;

  const int wm = (wave >> 2) << 7;   // 0 / 128
  const int wn = (wave & 3) << 6;    // 0 / 64 / 128 / 192

  // staging lane geometry: call = 512 lanes x 16B = 64 rows x 128B
  // pre-swizzled chunk (R2-verified, 0 conflicts): key = row&7 over 8 chunks
  const int srow   = tid >> 3;                  // row within call (0..63)
  const int schunk = (tid & 7) ^ (srow & 7);    // pre-swizzled 16B chunk
  const unsigned short* gA = A  + (size_t)(m0 + srow) * K + schunk * 8;
  const unsigned short* gB = Bt + (size_t)(n0 + srow) * K + schunk * 8;
  const int ldst = wave << 9;                   // wave LDS slice (ushorts)

  // fragment read geometry: lane (fr,q), sub k-half s: chunk = q + 4s,
  // slot = chunk ^ (fr&7); sub1 offset = sub0 ^ 32 (ushorts)
  const int fr = lane & 15, q = lane >> 4;
  const int cs0 = (q ^ (fr & 7)) << 3;
  const int ofsA0 = ((wm + fr) << 6) + cs0;
  const int ofsB0 = ((wn + fr) << 6) + cs0;
  const int ofsA1 = ofsA0 ^ 32;
  const int ofsB1 = ofsB0 ^ 32;

  f32x4 acc[8][4] = {};
  bf16x8 a0A[4], b0A[2], a0B[4], b0B[2];   // head sets (pre-issued a0,b0)
  bf16x8 a1A[4], b1A[2], a1B[4], b1B[2];   // tail sets (q4 carry a1,b1)

  unsigned short* A0p = &As[0][0]; unsigned short* B0p = &Bs[0][0];
  unsigned short* A1p = &As[1][0]; unsigned short* B1p = &Bs[1][0];

  // prologue: stage tile0 -> buf0 (8 calls), tile1 -> buf1 (8 calls);
  // vmcnt(8) = tile0 resident, tile1 in flight (ledger invariant).
#pragma unroll
  for (int c = 0; c < 4; ++c) {
    async16(gA + (size_t)(c * 64) * K,      A0p + c * 4096 + ldst);
    async16(gB + (size_t)(c * 64) * K,      B0p + c * 4096 + ldst);
  }
#pragma unroll
  for (int c = 0; c < 4; ++c) {
    async16(gA + (size_t)(c * 64) * K + 64, A1p + c * 4096 + ldst);
    async16(gB + (size_t)(c * 64) * K + 64, B1p + c * 4096 + ldst);
  }
  asm volatile("s_waitcnt vmcnt(8)" ::: "memory");
  __builtin_amdgcn_s_barrier();
  // pre-issue a0,b0 of tile0 sub0 (buf0)
#pragma unroll
  for (int i = 0; i < 4; ++i)
    a0A[i] = *(const bf16x8*)(A0p + ofsA0 + i * 1024);
#pragma unroll
  for (int j = 0; j < 2; ++j)
    b0A[j] = *(const bf16x8*)(B0p + ofsB0 + j * 1024);
  SBAR;

  const int NT = K >> 6;   // 16 (GEMM1) or 32 (GEMM2); even, >= 6

  // t = 0 (buf0): sub0 has no q4' yet
  ksub<false, false, false, -1, true>(A0p, B0p, A0p, B0p, A0p, B0p, gA, gB,
      0, K, ldst, ofsA0, ofsB0, ofsA1, ofsB1,
      a0A, b0A, a0B, b0B, a1B, b1B, a1A, b1A, acc);
  ksub<true, true, true, 8, true>(A0p, B0p, A0p, B0p, A1p, B1p, gA, gB,
      2 * 64, K, ldst, ofsA1, ofsB1, ofsA0, ofsB0,
      a0B, b0B, a0A, b0A, a1A, b1A, a1B, b1B, acc);

  // t = 1 .. NT-4 in pairs (buf1, buf0)
#pragma unroll 1
  for (int t = 1; t <= NT - 4; t += 2) {
    ksub<true, false, false, -1, true>(A1p, B1p, A1p, B1p, A1p, B1p, gA, gB,
        0, K, ldst, ofsA0, ofsB0, ofsA1, ofsB1,
        a0A, b0A, a0B, b0B, a1B, b1B, a1A, b1A, acc);
    ksub<true, true, true, 8, true>(A1p, B1p, A1p, B1p, A0p, B0p, gA, gB,
        (t + 2) * 64, K, ldst, ofsA1, ofsB1, ofsA0, ofsB0,
        a0B, b0B, a0A, b0A, a1A, b1A, a1B, b1B, acc);
    ksub<true, false, false, -1, true>(A0p, B0p, A0p, B0p, A0p, B0p, gA, gB,
        0, K, ldst, ofsA0, ofsB0, ofsA1, ofsB1,
        a0A, b0A, a0B, b0B, a1B, b1B, a1A, b1A, acc);
    ksub<true, true, true, 8, true>(A0p, B0p, A0p, B0p, A1p, B1p, gA, gB,
        (t + 3) * 64, K, ldst, ofsA1, ofsB1, ofsA0, ofsB0,
        a0B, b0B, a0A, b0A, a1A, b1A, a1B, b1B, acc);
  }
  // t = NT-3 (buf1): full, stages tile NT-1
  ksub<true, false, false, -1, true>(A1p, B1p, A1p, B1p, A1p, B1p, gA, gB,
      0, K, ldst, ofsA0, ofsB0, ofsA1, ofsB1,
      a0A, b0A, a0B, b0B, a1B, b1B, a1A, b1A, acc);
  ksub<true, true, true, 8, true>(A1p, B1p, A1p, B1p, A0p, B0p, gA, gB,
      (NT - 1) * 64, K, ldst, ofsA1, ofsB1, ofsA0, ofsB0,
      a0B, b0B, a0A, b0A, a1A, b1A, a1B, b1B, acc);
  // t = NT-2 (buf0): no stage; vmcnt(0) -> tile NT-1 resident
  ksub<true, false, false, -1, true>(A0p, B0p, A0p, B0p, A0p, B0p, gA, gB,
      0, K, ldst, ofsA0, ofsB0, ofsA1, ofsB1,
      a0A, b0A, a0B, b0B, a1B, b1B, a1A, b1A, acc);
  ksub<true, true, false, 0, true>(A0p, B0p, A0p, B0p, A1p, B1p, gA, gB,
      0, K, ldst, ofsA1, ofsB1, ofsA0, ofsB0,
      a0B, b0B, a0A, b0A, a1A, b1A, a1B, b1B, acc);
  // t = NT-1 (buf1): no barriers/staging
  ksub<true, false, false, -1, true>(A1p, B1p, A1p, B1p, A1p, B1p, gA, gB,
      0, K, ldst, ofsA0, ofsB0, ofsA1, ofsB1,
      a0A, b0A, a0B, b0B, a1B, b1B, a1A, b1A, acc);
  ksub<true, false, false, -1, false>(A1p, B1p, A1p, B1p, A1p, B1p, gA, gB,
      0, K, ldst, ofsA1, ofsB1, ofsA0, ofsB0,
      a0B, b0B, a0A, b0A, a1A, b1A, a1B, b1B, acc);
  // final q4 of last sub (tail set B)
  __builtin_amdgcn_s_setprio(1);
#pragma unroll
  for (int i = 0; i < 4; ++i)
#pragma unroll
    for (int j = 0; j < 2; ++j)
      acc[i + 4][j + 2] = MFMA_B16(a1B[i], b1B[j], acc[i + 4][j + 2]);
  __builtin_amdgcn_s_setprio(0);

  // epilogue: bias + optional relu; per-block output select (tile-aligned)
  // C/D layout: col = lane&15, row = (lane>>4)*4 + reg   [m89/m91 verified]
  // j INNERMOST: each 128B output line completed in 4 consecutive stores
  void* Cb = (m0 < Msplit) ? C0 : C1;
  const int mbase = (m0 < Msplit) ? m0 : (m0 - Msplit);
  const int crow = mbase + wm + (lane >> 4) * 4;
  const int ccol = n0 + wn + (lane & 15);
  float bv[4];
#pragma unroll
  for (int j = 0; j < 4; ++j) bv[j] = bias[ccol + j * 16];
#pragma unroll
  for (int i = 0; i < 8; ++i) {
#pragma unroll
    for (int r = 0; r < 4; ++r) {
      size_t base = (size_t)(crow + i * 16 + r) * N + ccol;
#pragma unroll
      for (int j = 0; j < 4; ++j) {
        float v = acc[i][j][r] + bv[j];
        if (RELU) v = fmaxf(v, 0.0f);
        if (OUT_BF16) ((unsigned short*)Cb)[base + j * 16] = f2bf(v);
        else          ((float*)Cb)[base + j * 16] = v;
      }
    }
  }
}

// ---------------------------------------------------------------------------
// post_kernel: comb (blocks [0, SUNL/2)) + yhat (blocks [SUNL/2, +SLAB/4))
// ---------------------------------------------------------------------------
#define COMB_BLOCKS (SUNL / 2)              // 8192
#define YHAT_BLOCKS (SLAB / 4)              // 2048
#define POST_BLOCKS (COMB_BLOCKS + YHAT_BLOCKS)

__global__ __launch_bounds__(256) void post_kernel(
    const float* __restrict__ feat_l, const float* __restrict__ W3,
    const float* __restrict__ b3, const int* __restrict__ ia,
    const int* __restrict__ ib, const float* __restrict__ kv,
    float* __restrict__ out_comb, float* __restrict__ out_yhat)
{
  int b = blockIdx.x;
  if (b < COMB_BLOCKS) {
    int row = b * 2 + (threadIdx.x >> 7);
    int c = (threadIdx.x & 127) << 2;
    float k = kv[row];
    float km1 = 1.0f - k;
    float4 fa = *(const float4*)(feat_l + (size_t)ia[row] * HID2 + c);
    float4 fb = *(const float4*)(feat_l + (size_t)ib[row] * HID2 + c);
    float4 o;
    o.x = k * fa.x + km1 * fb.x;
    o.y = k * fa.y + km1 * fb.y;
    o.z = k * fa.z + km1 * fb.z;
    o.w = k * fa.w + km1 * fb.w;
    *(float4*)(out_comb + (size_t)row * HID2 + c) = o;
  } else {
    int wave = threadIdx.x >> 6;
    int lane = threadIdx.x & 63;
    int row = (b - COMB_BLOCKS) * 4 + wave;
    const float* f = feat_l + (size_t)row * HID2;
    float s = 0.f;
#pragma unroll
    for (int j = 0; j < HID2 / 64; ++j) s = fmaf(f[lane + j * 64], W3[lane + j * 64], s);
#pragma unroll
    for (int off = 32; off; off >>= 1) s += __shfl_down(s, off);
    if (lane == 0) out_yhat[row] = s + b3[0];
  }
}

// ---------------------------------------------------------------------------
extern "C" void kernel_launch(void* const* d_in, const int* in_sizes, int n_in,
                              void* d_out, int out_size, void* d_ws, size_t ws_size,
                              hipStream_t stream)
{
  const float* X_l = (const float*)d_in[0];
  const float* y_l = (const float*)d_in[1];
  const float* X_u = (const float*)d_in[2];
  const float* y_u = (const float*)d_in[3];
  const float* W1  = (const float*)d_in[4];
  const float* b1  = (const float*)d_in[5];
  const float* W2  = (const float*)d_in[6];
  const float* b2  = (const float*)d_in[7];
  const float* W3  = (const float*)d_in[8];
  const float* b3  = (const float*)d_in[9];

  float* out_featu = (float*)d_out;
  float* out_comb  = out_featu + (size_t)SUNL * HID2;
  float* out_yhat  = out_comb + (size_t)SUNL * HID2;

  // Workspace (~174 MB): X_bf = [Xl|Xu] contig, H_bf = [Hl|Hu] contig
  unsigned short* X_bf  = (unsigned short*)d_ws;                 // [24576][1024]
  unsigned short* W1T   = X_bf + (size_t)MTOT * DIMX;
  unsigned short* W2T   = W1T + (size_t)HID1 * DIMX;
  unsigned short* H_bf  = W2T + (size_t)HID2 * HID1;             // [24576][2048]
  float* feat_l = (float*)(H_bf + (size_t)MTOT * HID1);
  int*   ai = (int*)(feat_l + (size_t)SLAB * HID2);
  int*   bi = ai + SUNL;
  float* kv = (float*)(bi + SUNL);

  prep_kernel<<<dim3(PREP_BLOCKS), dim3(256), 0, stream>>>(
      X_l, X_u, W1, W2, y_l, y_u, X_bf, W1T, W2T, ai, bi, kv);

  // layer 1 (merged l+u): H = relu(X @ W1 + b1) -> bf16  [768 blocks x 512]
  gemm_bt_256<1, 1><<<dim3((HID1 / 256) * (MTOT / 256)), dim3(512), 0, stream>>>(
      X_bf, W1T, b1, H_bf, H_bf, MTOT /*no split*/, MTOT, HID1, DIMX);

  // layer 2 (merged l+u): feat = relu(H @ W2 + b2) -> fp32, split dest [192 blocks]
  gemm_bt_256<0, 1><<<dim3((HID2 / 256) * (MTOT / 256)), dim3(512), 0, stream>>>(
      H_bf, W2T, b2, feat_l, out_featu, SLAB, MTOT, HID2, HID1);

  post_kernel<<<dim3(POST_BLOCKS), dim3(256), 0, stream>>>(
      feat_l, W3, b3, ai, bi, kv, out_comb, out_yhat);
}